// Round 2
// baseline (383.607 us; speedup 1.0000x reference)
//
#include <hip/hip_runtime.h>
#include <stdint.h>

// B=2, S=2048, D=1024, H=16, DK=64, DH=4096. I/O fp32; internals bf16 MFMA.
// R9: split-K deepened to 4 on the skinny GEMMs (Wo-proj, FFN2). grid
// 8x32x4 = 1024 blocks = 4 blocks/CU (was 2 -> Occupancy 18.6%, MfmaUtil 21%).
// No atomics: partials z=1..3 go to dead ws regions; the following LayerNorm
// folds the reduction (5-input LN: P0+P1+P2+P3+residual).

typedef unsigned short u16;
typedef __attribute__((ext_vector_type(8))) short v8s;   // 8 x bf16
typedef __attribute__((ext_vector_type(4))) float v4f;

#define AS1 __attribute__((address_space(1)))
#define AS3 __attribute__((address_space(3)))

__device__ __forceinline__ void gl_lds16(const u16* g, u16* l) {
  __builtin_amdgcn_global_load_lds((const AS1 void*)g, (AS3 void*)l, 16, 0, 0);
}

__device__ __forceinline__ float bf2f(u16 u) {
  union { uint32_t i; float f; } v; v.i = ((uint32_t)u) << 16; return v.f;
}
__device__ __forceinline__ u16 f2bf(float f) {
  union { float f; uint32_t i; } v; v.f = f;
  uint32_t x = v.i;
  return (u16)((x + 0x7FFFu + ((x >> 16) & 1u)) >> 16);  // RNE
}
__device__ __forceinline__ uint32_t fbits(float f) {
  union { float f; uint32_t u; } v; v.f = f; return v.u;
}

// ---------------------------------------------------------------------------
__global__ __launch_bounds__(256) void cvt_f2b(
    const float* __restrict__ src, u16* __restrict__ dst, int n4) {
  int i = (blockIdx.x * 256 + threadIdx.x);
  if (i < n4) {
    float4 v = *(const float4*)(src + (size_t)i * 4);
    ushort4 o;
    o.x = f2bf(v.x); o.y = f2bf(v.y); o.z = f2bf(v.z); o.w = f2bf(v.w);
    *(ushort4*)(dst + (size_t)i * 4) = o;
  }
}

// ---------------------------------------------------------------------------
__global__ __launch_bounds__(256) void transpose_f2b(
    const float* __restrict__ src, u16* __restrict__ dst,
    int R, int C, int ld_s, int ld_d) {
  __shared__ float tile[32][33];
  const int tx = threadIdx.x & 31, ty = threadIdx.x >> 5;
  const int c0 = blockIdx.x * 32, r0 = blockIdx.y * 32;
#pragma unroll
  for (int j = 0; j < 32; j += 8)
    tile[ty + j][tx] = src[(size_t)(r0 + ty + j) * ld_s + c0 + tx];
  __syncthreads();
#pragma unroll
  for (int j = 0; j < 32; j += 8)
    dst[(size_t)(c0 + ty + j) * ld_d + r0 + tx] = f2bf(tile[tx][ty + j]);
}

__global__ __launch_bounds__(256) void transpose_b2b(
    const u16* __restrict__ src, u16* __restrict__ dst,
    int R, int C, int ld_s, int ld_d) {
  __shared__ u16 tile[32][33];
  const int tx = threadIdx.x & 31, ty = threadIdx.x >> 5;
  const int c0 = blockIdx.x * 32, r0 = blockIdx.y * 32;
#pragma unroll
  for (int j = 0; j < 32; j += 8)
    tile[ty + j][tx] = src[(size_t)(r0 + ty + j) * ld_s + c0 + tx];
  __syncthreads();
#pragma unroll
  for (int j = 0; j < 32; j += 8)
    dst[(size_t)(c0 + ty + j) * ld_d + r0 + tx] = tile[tx][ty + j];
}

// ---------------------------------------------------------------------------
// G1: 128x128 tile, BK=32, double-buffered.
// ---------------------------------------------------------------------------
__global__ __launch_bounds__(256) void gemm_g1(
    const u16* __restrict__ A, const u16* __restrict__ Bt,
    const float* __restrict__ bias, void* __restrict__ C,
    int M, int N, int K, int relu, int out_f32) {
  __shared__ u16 As[2][4096];
  __shared__ u16 Bs[2][4096];
  const int tid = threadIdx.x;
  const int w = tid >> 6, l = tid & 63;
  const int lane16 = l & 15, kgrp = l >> 4;
  const int m0 = blockIdx.y * 128, n0 = blockIdx.x * 128;
  const int wr = (w >> 1) * 64, wc = (w & 1) * 64;

  const int sr = w * 32 + (l >> 2);
  const int sc = l & 3;
  const int sgc = sc ^ ((sr & 3) ^ ((sr >> 2) & 3));
  const u16* gA = A + (size_t)(m0 + sr) * K + 8 * sgc;
  const u16* gB = Bt + (size_t)(n0 + sr) * K + 8 * sgc;
  const size_t rstep = (size_t)16 * K;
  const int fl = (lane16 & 3) ^ ((lane16 >> 2) & 3);

  v4f acc[4][4];
#pragma unroll
  for (int i = 0; i < 4; i++)
#pragma unroll
    for (int j = 0; j < 4; j++)
#pragma unroll
      for (int r = 0; r < 4; r++) acc[i][j][r] = 0.f;

  gl_lds16(gA, &As[0][w * 1024]);
  gl_lds16(gA + rstep, &As[0][w * 1024 + 512]);
  gl_lds16(gB, &Bs[0][w * 1024]);
  gl_lds16(gB + rstep, &Bs[0][w * 1024 + 512]);

  int cur = 0;
  for (int k0 = 0; k0 < K; k0 += 32) {
    __syncthreads();
    if (k0 + 32 < K) {
      int nxt = cur ^ 1;
      gl_lds16(gA + k0 + 32, &As[nxt][w * 1024]);
      gl_lds16(gA + k0 + 32 + rstep, &As[nxt][w * 1024 + 512]);
      gl_lds16(gB + k0 + 32, &Bs[nxt][w * 1024]);
      gl_lds16(gB + k0 + 32 + rstep, &Bs[nxt][w * 1024 + 512]);
    }
    v8s a[4], b[4];
#pragma unroll
    for (int mi = 0; mi < 4; mi++)
      a[mi] = *(const v8s*)(&As[cur][(wr + mi * 16 + lane16) * 32 + 8 * (kgrp ^ fl)]);
#pragma unroll
    for (int ni = 0; ni < 4; ni++)
      b[ni] = *(const v8s*)(&Bs[cur][(wc + ni * 16 + lane16) * 32 + 8 * (kgrp ^ fl)]);
#pragma unroll
    for (int mi = 0; mi < 4; mi++)
#pragma unroll
      for (int ni = 0; ni < 4; ni++)
        acc[mi][ni] = __builtin_amdgcn_mfma_f32_16x16x32_bf16(a[mi], b[ni], acc[mi][ni], 0, 0, 0);
    cur ^= 1;
  }

#pragma unroll
  for (int ni = 0; ni < 4; ni++) {
    int col = n0 + wc + ni * 16 + lane16;
    float bv = bias ? bias[col] : 0.f;
#pragma unroll
    for (int mi = 0; mi < 4; mi++) {
      int row = m0 + wr + mi * 16 + kgrp * 4;
#pragma unroll
      for (int r = 0; r < 4; r++) {
        float v = acc[mi][ni][r] + bv;
        if (relu) v = fmaxf(v, 0.f);
        size_t idx = (size_t)(row + r) * N + col;
        if (out_f32) ((float*)C)[idx] = v;
        else ((u16*)C)[idx] = f2bf(v);
      }
    }
  }
}

// ---------------------------------------------------------------------------
// G1s: split-K=4 variant of G1 (blockIdx.z = split). 128x128 tile, BK=32.
// z=0 -> C0 (+bias, fp32 or bf16); z=1..3 -> C1/C2/C3 (bf16 partials).
// No atomics; reduction folded into the following 5-input LayerNorm.
// ---------------------------------------------------------------------------
__global__ __launch_bounds__(256) void gemm_g1s(
    const u16* __restrict__ A, const u16* __restrict__ Bt,
    const float* __restrict__ bias, void* __restrict__ C0,
    u16* __restrict__ C1, u16* __restrict__ C2, u16* __restrict__ C3,
    int M, int N, int ldk, int klen, int c0_f32) {
  __shared__ u16 As[2][4096];
  __shared__ u16 Bs[2][4096];
  const int tid = threadIdx.x;
  const int w = tid >> 6, l = tid & 63;
  const int lane16 = l & 15, kgrp = l >> 4;
  const int m0 = blockIdx.y * 128, n0 = blockIdx.x * 128;
  const int z = blockIdx.z;
  const int k_begin = z * klen;
  const int wr = (w >> 1) * 64, wc = (w & 1) * 64;

  const int sr = w * 32 + (l >> 2);
  const int sc = l & 3;
  const int sgc = sc ^ ((sr & 3) ^ ((sr >> 2) & 3));
  const u16* gA = A + (size_t)(m0 + sr) * ldk + k_begin + 8 * sgc;
  const u16* gB = Bt + (size_t)(n0 + sr) * ldk + k_begin + 8 * sgc;
  const size_t rstep = (size_t)16 * ldk;
  const int fl = (lane16 & 3) ^ ((lane16 >> 2) & 3);

  v4f acc[4][4];
#pragma unroll
  for (int i = 0; i < 4; i++)
#pragma unroll
    for (int j = 0; j < 4; j++)
#pragma unroll
      for (int r = 0; r < 4; r++) acc[i][j][r] = 0.f;

  gl_lds16(gA, &As[0][w * 1024]);
  gl_lds16(gA + rstep, &As[0][w * 1024 + 512]);
  gl_lds16(gB, &Bs[0][w * 1024]);
  gl_lds16(gB + rstep, &Bs[0][w * 1024 + 512]);

  int cur = 0;
  for (int k0 = 0; k0 < klen; k0 += 32) {
    __syncthreads();
    if (k0 + 32 < klen) {
      int nxt = cur ^ 1;
      gl_lds16(gA + k0 + 32, &As[nxt][w * 1024]);
      gl_lds16(gA + k0 + 32 + rstep, &As[nxt][w * 1024 + 512]);
      gl_lds16(gB + k0 + 32, &Bs[nxt][w * 1024]);
      gl_lds16(gB + k0 + 32 + rstep, &Bs[nxt][w * 1024 + 512]);
    }
    v8s a[4], b[4];
#pragma unroll
    for (int mi = 0; mi < 4; mi++)
      a[mi] = *(const v8s*)(&As[cur][(wr + mi * 16 + lane16) * 32 + 8 * (kgrp ^ fl)]);
#pragma unroll
    for (int ni = 0; ni < 4; ni++)
      b[ni] = *(const v8s*)(&Bs[cur][(wc + ni * 16 + lane16) * 32 + 8 * (kgrp ^ fl)]);
#pragma unroll
    for (int mi = 0; mi < 4; mi++)
#pragma unroll
      for (int ni = 0; ni < 4; ni++)
        acc[mi][ni] = __builtin_amdgcn_mfma_f32_16x16x32_bf16(a[mi], b[ni], acc[mi][ni], 0, 0, 0);
    cur ^= 1;
  }

  u16* Cp = (z == 1) ? C1 : ((z == 2) ? C2 : C3);
#pragma unroll
  for (int ni = 0; ni < 4; ni++) {
    int col = n0 + wc + ni * 16 + lane16;
    float bv = (bias && z == 0) ? bias[col] : 0.f;
#pragma unroll
    for (int mi = 0; mi < 4; mi++) {
      int row = m0 + wr + mi * 16 + kgrp * 4;
#pragma unroll
      for (int r = 0; r < 4; r++) {
        float v = acc[mi][ni][r] + bv;
        size_t idx = (size_t)(row + r) * N + col;
        if (z == 0) {
          if (c0_f32) ((float*)C0)[idx] = v;
          else ((u16*)C0)[idx] = f2bf(v);
        } else {
          Cp[idx] = f2bf(v);
        }
      }
    }
  }
}

// ---------------------------------------------------------------------------
// G2: 128x64 tile, BK=64, double-buffered (unsplit; Qproj + small path).
// ---------------------------------------------------------------------------
__global__ __launch_bounds__(256) void gemm_g2(
    const u16* __restrict__ A, const u16* __restrict__ Bt,
    const float* __restrict__ bias, void* __restrict__ C,
    int M, int N, int K, int relu, int accum, int out_f32) {
  __shared__ u16 As[2][8192];
  __shared__ u16 Bs[2][4096];
  const int tid = threadIdx.x;
  const int w = tid >> 6, l = tid & 63;
  const int l16 = l & 15, kgrp = l >> 4;
  const int m0 = blockIdx.y * 128, n0 = blockIdx.x * 64;
  const int wr = (w >> 1) * 64, wc = (w & 1) * 32;

  const int srow = w * 8 + (l >> 3);
  const u16* gA[4];
#pragma unroll
  for (int i = 0; i < 4; i++) {
    int r = i * 32 + srow;
    gA[i] = A + (size_t)(m0 + r) * K + 8 * ((l & 7) ^ (r & 7));
  }
  const u16* gB[2];
#pragma unroll
  for (int i = 0; i < 2; i++) {
    int r = i * 32 + srow;
    gB[i] = Bt + (size_t)(n0 + r) * K + 8 * ((l & 7) ^ (r & 7));
  }

  v4f acc[4][2];
#pragma unroll
  for (int i = 0; i < 4; i++)
#pragma unroll
    for (int j = 0; j < 2; j++)
#pragma unroll
      for (int r = 0; r < 4; r++) acc[i][j][r] = 0.f;

#pragma unroll
  for (int i = 0; i < 4; i++) gl_lds16(gA[i], &As[0][(i * 256 + w * 64) * 8]);
#pragma unroll
  for (int i = 0; i < 2; i++) gl_lds16(gB[i], &Bs[0][(i * 256 + w * 64) * 8]);

  int cur = 0;
  for (int k0 = 0; k0 < K; k0 += 64) {
    __syncthreads();
    if (k0 + 64 < K) {
      int nxt = cur ^ 1;
#pragma unroll
      for (int i = 0; i < 4; i++)
        gl_lds16(gA[i] + k0 + 64, &As[nxt][(i * 256 + w * 64) * 8]);
#pragma unroll
      for (int i = 0; i < 2; i++)
        gl_lds16(gB[i] + k0 + 64, &Bs[nxt][(i * 256 + w * 64) * 8]);
    }
    v8s a[4][2], b[2][2];
#pragma unroll
    for (int ks = 0; ks < 2; ks++) {
      int ch = 8 * ((ks * 4 + kgrp) ^ (l16 & 7));
#pragma unroll
      for (int mi = 0; mi < 4; mi++)
        a[mi][ks] = *(const v8s*)(&As[cur][(wr + mi * 16 + l16) * 64 + ch]);
#pragma unroll
      for (int ni = 0; ni < 2; ni++)
        b[ni][ks] = *(const v8s*)(&Bs[cur][(wc + ni * 16 + l16) * 64 + ch]);
    }
#pragma unroll
    for (int ks = 0; ks < 2; ks++)
#pragma unroll
      for (int mi = 0; mi < 4; mi++)
#pragma unroll
        for (int ni = 0; ni < 2; ni++)
          acc[mi][ni] = __builtin_amdgcn_mfma_f32_16x16x32_bf16(a[mi][ks], b[ni][ks], acc[mi][ni], 0, 0, 0);
    cur ^= 1;
  }

#pragma unroll
  for (int ni = 0; ni < 2; ni++) {
    int col = n0 + wc + ni * 16 + l16;
    float bv = bias ? bias[col] : 0.f;
#pragma unroll
    for (int mi = 0; mi < 4; mi++) {
      int row = m0 + wr + mi * 16 + kgrp * 4;
#pragma unroll
      for (int r = 0; r < 4; r++) {
        float v = acc[mi][ni][r] + bv;
        if (relu) v = fmaxf(v, 0.f);
        size_t idx = (size_t)(row + r) * N + col;
        if (out_f32) {
          float* Cf = (float*)C;
          if (accum) v += Cf[idx];
          Cf[idx] = v;
        } else {
          ((u16*)C)[idx] = f2bf(v);
        }
      }
    }
  }
}

// ---------------------------------------------------------------------------
// Attention (R5 structure): O = softmax(Q Q^T / sqrt(S)) Q per (b,h).
// ---------------------------------------------------------------------------
__global__ __launch_bounds__(256) void attn_kernel(
    const u16* __restrict__ Q, const u16* __restrict__ Qt,
    u16* __restrict__ O) {
  __shared__ u16 KV[2][8192];
  __shared__ __align__(16) u16 Ps[4][2304];
  const int tid = threadIdx.x;
  const int w = tid >> 6, l = tid & 63;
  const int l16 = l & 15, kgrp = l >> 4;
  const int bh = blockIdx.y, b = bh >> 4, h = bh & 15;
  const int q0 = blockIdx.x * 128;
  const size_t rowQ = (size_t)(b * 2048 + q0 + w * 32);
  const float cexp = 1.4426950408889634f / 45.254833995939045f;

  const int srow = w * 8 + (l >> 3);
  const int sch8 = 8 * ((l & 7) ^ (srow & 7));
  const u16* gK0 = Q + (size_t)(b * 2048 + srow) * 1024 + h * 64 + sch8;
  const u16* gK1 = gK0 + (size_t)32 * 1024;
  const u16* gV0 = Qt + (size_t)(h * 64 + srow) * 4096 + b * 2048 + sch8;
  const u16* gV1 = gV0 + (size_t)32 * 4096;

  v8s qb[2][2];
#pragma unroll
  for (int nj = 0; nj < 2; nj++)
#pragma unroll
    for (int ks = 0; ks < 2; ks++) {
      v8s t = *(const v8s*)(Q + (rowQ + nj * 16 + l16) * 1024 + h * 64 + ks * 32 + kgrp * 8);
#pragma unroll
      for (int j = 0; j < 8; j++) t[j] = (short)f2bf(bf2f((u16)t[j]) * cexp);
      qb[nj][ks] = t;
    }

  v4f o[2][4];
  float ls[2] = {0.f, 0.f};
#pragma unroll
  for (int i = 0; i < 2; i++)
#pragma unroll
    for (int j = 0; j < 4; j++)
#pragma unroll
      for (int r = 0; r < 4; r++) o[i][j][r] = 0.f;

  gl_lds16(gK0, &KV[0][w * 512]);
  gl_lds16(gK1, &KV[0][2048 + w * 512]);
  gl_lds16(gV0, &KV[0][4096 + w * 512]);
  gl_lds16(gV1, &KV[0][4096 + 2048 + w * 512]);

  u16* Pw = &Ps[w][0];
  int cur = 0;
  for (int kb = 0; kb < 2048; kb += 64) {
    __syncthreads();
    if (kb + 64 < 2048) {
      int nxt = cur ^ 1;
      gl_lds16(gK0 + (size_t)(kb + 64) * 1024, &KV[nxt][w * 512]);
      gl_lds16(gK1 + (size_t)(kb + 64) * 1024, &KV[nxt][2048 + w * 512]);
      gl_lds16(gV0 + (kb + 64), &KV[nxt][4096 + w * 512]);
      gl_lds16(gV1 + (kb + 64), &KV[nxt][4096 + 2048 + w * 512]);
    }
    const u16* Ks = &KV[cur][0];
    const u16* Vt = &KV[cur][4096];

    v4f st[4][2];
#pragma unroll
    for (int i = 0; i < 4; i++)
#pragma unroll
      for (int j = 0; j < 2; j++)
#pragma unroll
        for (int r = 0; r < 4; r++) st[i][j][r] = 0.f;
#pragma unroll
    for (int ks = 0; ks < 2; ks++) {
      v8s ka[4];
#pragma unroll
      for (int mi = 0; mi < 4; mi++)
        ka[mi] = *(const v8s*)(Ks + (mi * 16 + l16) * 64 + 8 * ((ks * 4 + kgrp) ^ (l16 & 7)));
#pragma unroll
      for (int mi = 0; mi < 4; mi++)
#pragma unroll
        for (int nj = 0; nj < 2; nj++)
          st[mi][nj] = __builtin_amdgcn_mfma_f32_16x16x32_bf16(ka[mi], qb[nj][ks], st[mi][nj], 0, 0, 0);
    }

#pragma unroll
    for (int mi = 0; mi < 4; mi++)
#pragma unroll
      for (int nj = 0; nj < 2; nj++) {
        float p0 = __builtin_amdgcn_exp2f(st[mi][nj][0]);
        float p1 = __builtin_amdgcn_exp2f(st[mi][nj][1]);
        float p2 = __builtin_amdgcn_exp2f(st[mi][nj][2]);
        float p3 = __builtin_amdgcn_exp2f(st[mi][nj][3]);
        ls[nj] += (p0 + p1) + (p2 + p3);
        uint2 pk;
        pk.x = __builtin_amdgcn_perm(fbits(p1), fbits(p0), 0x07060302u);
        pk.y = __builtin_amdgcn_perm(fbits(p3), fbits(p2), 0x07060302u);
        *(uint2*)(Pw + (nj * 16 + l16) * 72 + mi * 16 + kgrp * 4) = pk;
      }

#pragma unroll
    for (int t = 0; t < 2; t++) {
      v8s pa[2], vb[4];
#pragma unroll
      for (int nj = 0; nj < 2; nj++)
        pa[nj] = *(const v8s*)(Pw + (nj * 16 + l16) * 72 + t * 32 + kgrp * 8);
#pragma unroll
      for (int ni = 0; ni < 4; ni++)
        vb[ni] = *(const v8s*)(Vt + (ni * 16 + l16) * 64 + 8 * ((t * 4 + kgrp) ^ (l16 & 7)));
#pragma unroll
      for (int nj = 0; nj < 2; nj++)
#pragma unroll
        for (int ni = 0; ni < 4; ni++)
          o[nj][ni] = __builtin_amdgcn_mfma_f32_16x16x32_bf16(pa[nj], vb[ni], o[nj][ni], 0, 0, 0);
    }
    cur ^= 1;
  }

#pragma unroll
  for (int nj = 0; nj < 2; nj++) {
    float t = ls[nj];
    t += __shfl_xor(t, 16, 64);
    t += __shfl_xor(t, 32, 64);
    ls[nj] = t;
  }

#pragma unroll
  for (int nj = 0; nj < 2; nj++) {
#pragma unroll
    for (int r = 0; r < 4; r++) {
      float den = __shfl(ls[nj], kgrp * 4 + r, 64);
      float rden = 1.f / den;
#pragma unroll
      for (int ni = 0; ni < 4; ni++) {
        O[(rowQ + nj * 16 + kgrp * 4 + r) * 1024 + h * 64 + ni * 16 + l16] =
            f2bf(o[nj][ni][r] * rden);
      }
    }
  }
}

// ---------------------------------------------------------------------------
// out = LayerNorm(Y [+ Y2 + Y3 + Y4] + Xr) * g + b; row length 1024; dtype
// flags (1 = fp32, 0 = bf16). Y2/Y3/Y4 nullable (Y3/Y4 always bf16).
// In-place safe.
// ---------------------------------------------------------------------------
__global__ __launch_bounds__(256) void ln_residual(
    const void* __restrict__ Y, const void* __restrict__ Y2,
    const void* __restrict__ Y3, const void* __restrict__ Y4,
    const void* __restrict__ Xr,
    const float* __restrict__ g, const float* __restrict__ bb,
    void* __restrict__ out, int yf, int y2f, int xf, int of) {
  const int row = blockIdx.x, tid = threadIdx.x;
  const size_t base = (size_t)row * 1024;
  float v[4], s = 0.f, sq = 0.f;
#pragma unroll
  for (int i = 0; i < 4; i++) {
    int c = tid + i * 256;
    float ya = yf ? ((const float*)Y)[base + c] : bf2f(((const u16*)Y)[base + c]);
    float xa = xf ? ((const float*)Xr)[base + c] : bf2f(((const u16*)Xr)[base + c]);
    float x = ya + xa;
    if (Y2) {
      float y2a = y2f ? ((const float*)Y2)[base + c] : bf2f(((const u16*)Y2)[base + c]);
      x += y2a;
    }
    if (Y3) x += bf2f(((const u16*)Y3)[base + c]);
    if (Y4) x += bf2f(((const u16*)Y4)[base + c]);
    v[i] = x; s += x; sq += x * x;
  }
#pragma unroll
  for (int off = 32; off >= 1; off >>= 1) {
    s += __shfl_down(s, off, 64);
    sq += __shfl_down(sq, off, 64);
  }
  __shared__ float rs[4], rq[4];
  const int w = tid >> 6, l = tid & 63;
  if (l == 0) { rs[w] = s; rq[w] = sq; }
  __syncthreads();
  s = rs[0] + rs[1] + rs[2] + rs[3];
  sq = rq[0] + rq[1] + rq[2] + rq[3];
  const float mu = s * (1.f / 1024.f);
  const float var = sq * (1.f / 1024.f) - mu * mu;
  const float rstd = rsqrtf(var + 1e-5f);
#pragma unroll
  for (int i = 0; i < 4; i++) {
    int c = tid + i * 256;
    float r = (v[i] - mu) * rstd * g[c] + bb[c];
    if (of) ((float*)out)[base + c] = r;
    else ((u16*)out)[base + c] = f2bf(r);
  }
}

// ---------------------------------------------------------------------------
extern "C" void kernel_launch(void* const* d_in, const int* in_sizes, int n_in,
                              void* d_out, int out_size, void* d_ws, size_t ws_size,
                              hipStream_t stream) {
  const float* x   = (const float*)d_in[0];
  const float* Wq  = (const float*)d_in[1];
  const float* bq  = (const float*)d_in[2];
  const float* Wo  = (const float*)d_in[3];
  const float* bo  = (const float*)d_in[4];
  const float* g1  = (const float*)d_in[5];
  const float* be1 = (const float*)d_in[6];
  const float* W1  = (const float*)d_in[7];
  const float* b1  = (const float*)d_in[8];
  const float* W2  = (const float*)d_in[9];
  const float* b2  = (const float*)d_in[10];
  const float* g2  = (const float*)d_in[11];
  const float* be2 = (const float*)d_in[12];
  float* out = (float*)d_out;
  u16* ws  = (u16*)d_ws;

  const size_t M1 = 1048576;
  dim3 blk(256);
  const bool big = ws_size >= (size_t)37 * M1 * 2;  // 74 MiB

  if (big) {
    u16* xb   = ws + 0;          // [0..4M)  -> attn -> P2_ffn2
    u16* Qb   = ws + 4 * M1;     // [4..8M)  -> x1
    u16* Qt   = ws + 8 * M1;     // [8..12M) -> Yb (Wo P0) -> P1_ffn2
    u16* WqT  = ws + 12 * M1;    // [12..13M) -> WoT
    u16* W1T  = ws + 13 * M1;    // [13..17M) P1_wo -> W1T -> P3_ffn2
    u16* W2T  = ws + 17 * M1;    // [17..21M) P2_wo -> W2T
    u16* Hh   = ws + 21 * M1;    // [21..37M) P3_wo (head) -> Hh
    u16* attn = xb;  u16* Yb = Qt;  u16* x1 = Qb;  u16* WoT = WqT;
    // Wo split-4 partials: dead regions until later writers run (all after LN1)
    u16* P1wo = W1T;             // overwritten by transpose(W1) after LN1
    u16* P2wo = W2T;             // overwritten by transpose(W2) after FFN1
    u16* P3wo = Hh;              // overwritten by FFN1 after LN1
    // FFN2 split-4 partials: dead after their last reads
    u16* P1f2 = Qt;              // Yb dead after LN1
    u16* P2f2 = xb;              // attn dead after Wo-proj
    u16* P3f2 = W1T;             // W1T dead after FFN1

    cvt_f2b<<<dim3(4096), blk, 0, stream>>>(x, xb, 1048576);
    transpose_f2b<<<dim3(32, 32), blk, 0, stream>>>(Wq, WqT, 1024, 1024, 1024, 1024);
    gemm_g2<<<dim3(16, 32), blk, 0, stream>>>(xb, WqT, bq, Qb, 4096, 1024, 1024, 0, 0, 0);

    transpose_b2b<<<dim3(32, 128), blk, 0, stream>>>(Qb, Qt, 4096, 1024, 1024, 4096);
    attn_kernel<<<dim3(16, 32), blk, 0, stream>>>(Qb, Qt, attn);

    // Wo projection: split-K=4 (128x128 tile), P0 -> Yb (bf16, +bias)
    transpose_f2b<<<dim3(32, 32), blk, 0, stream>>>(Wo, WoT, 1024, 1024, 1024, 1024);
    gemm_g1s<<<dim3(8, 32, 4), blk, 0, stream>>>(attn, WoT, bo, Yb, P1wo, P2wo, P3wo,
                                                 4096, 1024, 1024, 256, 0);
    ln_residual<<<dim3(4096), blk, 0, stream>>>(Yb, P1wo, P2wo, P3wo, x, g1, be1, x1,
                                                0, 0, 1, 0);

    // FFN1: full-K 128x128
    transpose_f2b<<<dim3(128, 32), blk, 0, stream>>>(W1, W1T, 1024, 4096, 4096, 1024);
    gemm_g1<<<dim3(32, 32), blk, 0, stream>>>(x1, W1T, b1, Hh, 4096, 4096, 1024, 1, 0);

    // FFN2: split-K=4 (128x128 tile), P0 -> out (fp32, +bias)
    transpose_f2b<<<dim3(32, 128), blk, 0, stream>>>(W2, W2T, 4096, 1024, 1024, 4096);
    gemm_g1s<<<dim3(8, 32, 4), blk, 0, stream>>>(Hh, W2T, b2, out, P1f2, P2f2, P3f2,
                                                 4096, 1024, 4096, 1024, 1);

    ln_residual<<<dim3(4096), blk, 0, stream>>>(out, P1f2, P2f2, P3f2, x1, g2, be2, out,
                                                1, 0, 0, 1);
  } else {
    u16* xb   = ws + 0;
    u16* Qb   = ws + 4 * M1;
    u16* Qt   = ws + 8 * M1;
    u16* attn = xb;  u16* Yb = Qt;  u16* x1 = Qb;  u16* Hc = xb;
    u16* Wt1  = ws + 12 * M1;
    u16* Wt2  = ws + 13 * M1;

    cvt_f2b<<<dim3(4096), blk, 0, stream>>>(x, xb, 1048576);
    transpose_f2b<<<dim3(32, 32), blk, 0, stream>>>(Wq, Wt1, 1024, 1024, 1024, 1024);
    gemm_g2<<<dim3(16, 32), blk, 0, stream>>>(xb, Wt1, bq, Qb, 4096, 1024, 1024, 0, 0, 0);

    transpose_b2b<<<dim3(32, 128), blk, 0, stream>>>(Qb, Qt, 4096, 1024, 1024, 4096);
    attn_kernel<<<dim3(16, 32), blk, 0, stream>>>(Qb, Qt, attn);

    transpose_f2b<<<dim3(32, 32), blk, 0, stream>>>(Wo, Wt2, 1024, 1024, 1024, 1024);
    gemm_g2<<<dim3(16, 32), blk, 0, stream>>>(attn, Wt2, bo, Yb, 4096, 1024, 1024, 0, 0, 0);
    ln_residual<<<dim3(4096), blk, 0, stream>>>(Yb, nullptr, nullptr, nullptr, x, g1, be1,
                                                x1, 0, 0, 1, 0);

    for (int c = 0; c < 4; c++) {
      transpose_f2b<<<dim3(32, 32), blk, 0, stream>>>(W1 + (size_t)c * 1024, Wt1,
                                                      1024, 1024, 4096, 1024);
      gemm_g2<<<dim3(16, 32), blk, 0, stream>>>(x1, Wt1, b1 + (size_t)c * 1024, Hc,
                                                4096, 1024, 1024, 1, 0, 0);
      transpose_f2b<<<dim3(32, 32), blk, 0, stream>>>(W2 + (size_t)c * M1, Wt2,
                                                      1024, 1024, 1024, 1024);
      gemm_g2<<<dim3(16, 32), blk, 0, stream>>>(Hc, Wt2, (c == 0) ? b2 : (const float*)nullptr,
                                                out, 4096, 1024, 1024, 0, (c > 0) ? 1 : 0, 1);
    }
    ln_residual<<<dim3(4096), blk, 0, stream>>>(out, nullptr, nullptr, nullptr, x1, g2, be2,
                                                out, 1, 0, 0, 1);
  }
}

// Round 3
// 347.552 us; speedup vs baseline: 1.1037x; 1.1037x over previous
//
#include <hip/hip_runtime.h>
#include <stdint.h>

// B=2, S=2048, D=1024, H=16, DK=64, DH=4096. I/O fp32; internals bf16 MFMA.
// R10: phase-pipelined 256x256/BK=64 GEMM (gemm_8p) with counted vmcnt
// (never 0 in steady state), raw s_barrier (no drain), 2 barriers/K-tile.
// Used for FFN1 (unsplit, 256 blocks = 1/CU), FFN2 + Wo-proj (split-K=4,
// 256 blocks, partials folded by 5-input LayerNorm; no atomics).

typedef unsigned short u16;
typedef __attribute__((ext_vector_type(8))) short v8s;   // 8 x bf16
typedef __attribute__((ext_vector_type(4))) float v4f;

#define AS1 __attribute__((address_space(1)))
#define AS3 __attribute__((address_space(3)))

__device__ __forceinline__ void gl_lds16(const u16* g, u16* l) {
  __builtin_amdgcn_global_load_lds((const AS1 void*)g, (AS3 void*)l, 16, 0, 0);
}

__device__ __forceinline__ float bf2f(u16 u) {
  union { uint32_t i; float f; } v; v.i = ((uint32_t)u) << 16; return v.f;
}
__device__ __forceinline__ u16 f2bf(float f) {
  union { float f; uint32_t i; } v; v.f = f;
  uint32_t x = v.i;
  return (u16)((x + 0x7FFFu + ((x >> 16) & 1u)) >> 16);  // RNE
}
__device__ __forceinline__ uint32_t fbits(float f) {
  union { float f; uint32_t u; } v; v.f = f; return v.u;
}

// ---------------------------------------------------------------------------
__global__ __launch_bounds__(256) void cvt_f2b(
    const float* __restrict__ src, u16* __restrict__ dst, int n4) {
  int i = (blockIdx.x * 256 + threadIdx.x);
  if (i < n4) {
    float4 v = *(const float4*)(src + (size_t)i * 4);
    ushort4 o;
    o.x = f2bf(v.x); o.y = f2bf(v.y); o.z = f2bf(v.z); o.w = f2bf(v.w);
    *(ushort4*)(dst + (size_t)i * 4) = o;
  }
}

// ---------------------------------------------------------------------------
__global__ __launch_bounds__(256) void transpose_f2b(
    const float* __restrict__ src, u16* __restrict__ dst,
    int R, int C, int ld_s, int ld_d) {
  __shared__ float tile[32][33];
  const int tx = threadIdx.x & 31, ty = threadIdx.x >> 5;
  const int c0 = blockIdx.x * 32, r0 = blockIdx.y * 32;
#pragma unroll
  for (int j = 0; j < 32; j += 8)
    tile[ty + j][tx] = src[(size_t)(r0 + ty + j) * ld_s + c0 + tx];
  __syncthreads();
#pragma unroll
  for (int j = 0; j < 32; j += 8)
    dst[(size_t)(c0 + ty + j) * ld_d + r0 + tx] = f2bf(tile[tx][ty + j]);
}

__global__ __launch_bounds__(256) void transpose_b2b(
    const u16* __restrict__ src, u16* __restrict__ dst,
    int R, int C, int ld_s, int ld_d) {
  __shared__ u16 tile[32][33];
  const int tx = threadIdx.x & 31, ty = threadIdx.x >> 5;
  const int c0 = blockIdx.x * 32, r0 = blockIdx.y * 32;
#pragma unroll
  for (int j = 0; j < 32; j += 8)
    tile[ty + j][tx] = src[(size_t)(r0 + ty + j) * ld_s + c0 + tx];
  __syncthreads();
#pragma unroll
  for (int j = 0; j < 32; j += 8)
    dst[(size_t)(c0 + ty + j) * ld_d + r0 + tx] = tile[tx][ty + j];
}

// ---------------------------------------------------------------------------
// gemm_8p: 256x256 tile, BK=64, 512 threads (8 waves: 2M x 4N), 128 KiB LDS,
// phase-pipelined K-loop with counted vmcnt. blockIdx.z = K-split (klen per z).
// z==0 -> C0 (+bias, relu, fp32 or bf16); z=1..3 -> C1/C2/C3 bf16 partials.
//
// Per K-tile (4 phases, quadrant zigzag (mh,nh): (0,0)->(0,1)->(1,1)->(1,0)):
//   P1: read A-mh0 (8 ds_read) + B-nh0 (4); stage next A j=0,2;      MFMA 16
//   P2: read B-nh1 (4);          stage next B j=0,1; vmcnt(4)+bar;   MFMA 16
//   P3: read A-mh1 (8);          stage next B j=2,3;                 MFMA 16
//   P4:                          stage next A j=1,3; vmcnt(2)+bar;   MFMA 16
// Ledger (per wave, 2 loads/stage-pair): entering tile kt outstanding <= 2
// (= A13(kt)); P2's vmcnt(4) retires A13(kt) (needed by P3); P4's vmcnt(2)
// retires A02,B01,B23(kt+1) (needed by kt+1 P1/P2). Last tile peeled with a
// single vmcnt(0). Raw s_barrier only (no vmcnt(0)/lgkmcnt(0) drain).
// ---------------------------------------------------------------------------
__global__ __launch_bounds__(512, 1) void gemm_8p(
    const u16* __restrict__ A, const u16* __restrict__ Bt,
    const float* __restrict__ bias, void* __restrict__ C0,
    u16* __restrict__ C1, u16* __restrict__ C2, u16* __restrict__ C3,
    int M, int N, int ldk, int klen, int relu, int c0_f32) {
  __shared__ u16 As[2][16384];   // [buf][row*64 + elem], 256 rows x 64 k
  __shared__ u16 Bs[2][16384];
  const int tid = threadIdx.x;
  const int w = tid >> 6, l = tid & 63;
  const int l16 = l & 15, kgrp = (l >> 4) & 3;
  const int wm = w >> 2, wn = w & 3;
  const int m0 = blockIdx.y * 256, n0 = blockIdx.x * 256;
  const int z = blockIdx.z;
  const int NT = klen >> 6;

  // staging: thread covers row_local = tid>>3 (0..63) of each 64-row group j,
  // chunk tid&7; global source pre-swizzled by row&7 (linear LDS dest).
  const int rl = tid >> 3;
  const int sw = 8 * ((tid & 7) ^ (rl & 7));
  const u16* gA[4]; const u16* gB[4];
#pragma unroll
  for (int j = 0; j < 4; j++) {
    gA[j] = A + (size_t)(m0 + j * 64 + rl) * ldk + (size_t)z * klen + sw;
    gB[j] = Bt + (size_t)(n0 + j * 64 + rl) * ldk + (size_t)z * klen + sw;
  }
  const int sdst = w * 512;   // wave-uniform LDS base (+ j*4096)

  // fragment read addressing (row&7 == l16&7 for all fragment rows)
  const int ch0 = 8 * ((kgrp) ^ (l16 & 7));
  const int ch1 = 8 * ((4 + kgrp) ^ (l16 & 7));
  const int abase = (wm * 128 + l16) * 64;
  const int bbase = (wn * 64 + l16) * 64;

  v4f acc[8][4];
#pragma unroll
  for (int i = 0; i < 8; i++)
#pragma unroll
    for (int j = 0; j < 4; j++)
#pragma unroll
      for (int r = 0; r < 4; r++) acc[i][j][r] = 0.f;

  v8s a[4][2], b[4][2];

#define FENCE() asm volatile("" ::: "memory")
#define VMC(n) asm volatile("s_waitcnt vmcnt(" #n ")" ::: "memory")
#define BARX() { __builtin_amdgcn_s_barrier(); \
                 __builtin_amdgcn_sched_barrier(0); FENCE(); }
#define STGA(q, j, kt) gl_lds16(gA[j] + (size_t)(kt) * 64, &As[q][(j) * 4096 + sdst])
#define STGB(q, j, kt) gl_lds16(gB[j] + (size_t)(kt) * 64, &Bs[q][(j) * 4096 + sdst])
#define LDA(p, mh) { \
  const u16* Ap = &As[p][abase + (mh) * 4096]; \
  _Pragma("unroll") for (int mi = 0; mi < 4; mi++) { \
    a[mi][0] = *(const v8s*)(Ap + mi * 1024 + ch0); \
    a[mi][1] = *(const v8s*)(Ap + mi * 1024 + ch1); } }
#define LDB(p, nh) { \
  const u16* Bp = &Bs[p][bbase + (nh) * 2048]; \
  _Pragma("unroll") for (int ni = 0; ni < 2; ni++) { \
    b[(nh) * 2 + ni][0] = *(const v8s*)(Bp + ni * 1024 + ch0); \
    b[(nh) * 2 + ni][1] = *(const v8s*)(Bp + ni * 1024 + ch1); } }
#define MFQ(mh, nh) { \
  __builtin_amdgcn_s_setprio(1); \
  _Pragma("unroll") for (int ks = 0; ks < 2; ks++) \
  _Pragma("unroll") for (int mi = 0; mi < 4; mi++) \
  _Pragma("unroll") for (int ni = 0; ni < 2; ni++) \
    acc[(mh) * 4 + mi][(nh) * 2 + ni] = __builtin_amdgcn_mfma_f32_16x16x32_bf16( \
        a[mi][ks], b[(nh) * 2 + ni][ks], acc[(mh) * 4 + mi][(nh) * 2 + ni], 0, 0, 0); \
  __builtin_amdgcn_s_setprio(0); }

  // prologue: stage tile 0 into buf0, need-first order: A02, B01, B23, A13
  STGA(0, 0, 0); STGA(0, 2, 0);
  FENCE();
  STGB(0, 0, 0); STGB(0, 1, 0);
  FENCE();
  STGB(0, 2, 0); STGB(0, 3, 0);
  FENCE();
  STGA(0, 1, 0); STGA(0, 3, 0);
  VMC(2); BARX();

  int p = 0;
  for (int kt = 0; kt < NT - 1; ++kt, p ^= 1) {
    const int q = p ^ 1;
    const int kn = kt + 1;
    // P1
    LDA(p, 0);
    LDB(p, 0);
    FENCE();
    STGA(q, 0, kn); STGA(q, 2, kn);
    MFQ(0, 0);
    // P2
    LDB(p, 1);
    FENCE();
    STGB(q, 0, kn); STGB(q, 1, kn);
    VMC(4); BARX();
    MFQ(0, 1);
    // P3
    LDA(p, 1);
    FENCE();
    STGB(q, 2, kn); STGB(q, 3, kn);
    MFQ(1, 1);
    // P4
    FENCE();
    STGA(q, 1, kn); STGA(q, 3, kn);
    VMC(2); BARX();
    MFQ(1, 0);
  }
  // peeled last tile: everything must be landed; no staging, no barriers.
  VMC(0); BARX();
  LDA(p, 0);
  LDB(p, 0);
  MFQ(0, 0);
  LDB(p, 1);
  MFQ(0, 1);
  LDA(p, 1);
  MFQ(1, 1);
  MFQ(1, 0);

#undef FENCE
#undef VMC
#undef BARX
#undef STGA
#undef STGB
#undef LDA
#undef LDB
#undef MFQ

#pragma unroll
  for (int mi = 0; mi < 8; mi++) {
    const int row = m0 + wm * 128 + mi * 16 + kgrp * 4;
#pragma unroll
    for (int ni = 0; ni < 4; ni++) {
      const int col = n0 + wn * 64 + ni * 16 + l16;
      float bv = (bias && z == 0) ? bias[col] : 0.f;
#pragma unroll
      for (int r = 0; r < 4; r++) {
        float v = acc[mi][ni][r] + bv;
        if (z == 0 && relu) v = fmaxf(v, 0.f);
        size_t idx = (size_t)(row + r) * N + col;
        if (z == 0) {
          if (c0_f32) ((float*)C0)[idx] = v;
          else ((u16*)C0)[idx] = f2bf(v);
        } else if (z == 1) {
          C1[idx] = f2bf(v);
        } else if (z == 2) {
          C2[idx] = f2bf(v);
        } else {
          C3[idx] = f2bf(v);
        }
      }
    }
  }
}

// ---------------------------------------------------------------------------
// G2: 128x64 tile, BK=64, double-buffered (Qproj + small path).
// ---------------------------------------------------------------------------
__global__ __launch_bounds__(256) void gemm_g2(
    const u16* __restrict__ A, const u16* __restrict__ Bt,
    const float* __restrict__ bias, void* __restrict__ C,
    int M, int N, int K, int relu, int accum, int out_f32) {
  __shared__ u16 As[2][8192];
  __shared__ u16 Bs[2][4096];
  const int tid = threadIdx.x;
  const int w = tid >> 6, l = tid & 63;
  const int l16 = l & 15, kgrp = l >> 4;
  const int m0 = blockIdx.y * 128, n0 = blockIdx.x * 64;
  const int wr = (w >> 1) * 64, wc = (w & 1) * 32;

  const int srow = w * 8 + (l >> 3);
  const u16* gA[4];
#pragma unroll
  for (int i = 0; i < 4; i++) {
    int r = i * 32 + srow;
    gA[i] = A + (size_t)(m0 + r) * K + 8 * ((l & 7) ^ (r & 7));
  }
  const u16* gB[2];
#pragma unroll
  for (int i = 0; i < 2; i++) {
    int r = i * 32 + srow;
    gB[i] = Bt + (size_t)(n0 + r) * K + 8 * ((l & 7) ^ (r & 7));
  }

  v4f acc[4][2];
#pragma unroll
  for (int i = 0; i < 4; i++)
#pragma unroll
    for (int j = 0; j < 2; j++)
#pragma unroll
      for (int r = 0; r < 4; r++) acc[i][j][r] = 0.f;

#pragma unroll
  for (int i = 0; i < 4; i++) gl_lds16(gA[i], &As[0][(i * 256 + w * 64) * 8]);
#pragma unroll
  for (int i = 0; i < 2; i++) gl_lds16(gB[i], &Bs[0][(i * 256 + w * 64) * 8]);

  int cur = 0;
  for (int k0 = 0; k0 < K; k0 += 64) {
    __syncthreads();
    if (k0 + 64 < K) {
      int nxt = cur ^ 1;
#pragma unroll
      for (int i = 0; i < 4; i++)
        gl_lds16(gA[i] + k0 + 64, &As[nxt][(i * 256 + w * 64) * 8]);
#pragma unroll
      for (int i = 0; i < 2; i++)
        gl_lds16(gB[i] + k0 + 64, &Bs[nxt][(i * 256 + w * 64) * 8]);
    }
    v8s a[4][2], b[2][2];
#pragma unroll
    for (int ks = 0; ks < 2; ks++) {
      int ch = 8 * ((ks * 4 + kgrp) ^ (l16 & 7));
#pragma unroll
      for (int mi = 0; mi < 4; mi++)
        a[mi][ks] = *(const v8s*)(&As[cur][(wr + mi * 16 + l16) * 64 + ch]);
#pragma unroll
      for (int ni = 0; ni < 2; ni++)
        b[ni][ks] = *(const v8s*)(&Bs[cur][(wc + ni * 16 + l16) * 64 + ch]);
    }
#pragma unroll
    for (int ks = 0; ks < 2; ks++)
#pragma unroll
      for (int mi = 0; mi < 4; mi++)
#pragma unroll
        for (int ni = 0; ni < 2; ni++)
          acc[mi][ni] = __builtin_amdgcn_mfma_f32_16x16x32_bf16(a[mi][ks], b[ni][ks], acc[mi][ni], 0, 0, 0);
    cur ^= 1;
  }

#pragma unroll
  for (int ni = 0; ni < 2; ni++) {
    int col = n0 + wc + ni * 16 + l16;
    float bv = bias ? bias[col] : 0.f;
#pragma unroll
    for (int mi = 0; mi < 4; mi++) {
      int row = m0 + wr + mi * 16 + kgrp * 4;
#pragma unroll
      for (int r = 0; r < 4; r++) {
        float v = acc[mi][ni][r] + bv;
        if (relu) v = fmaxf(v, 0.f);
        size_t idx = (size_t)(row + r) * N + col;
        if (out_f32) {
          float* Cf = (float*)C;
          if (accum) v += Cf[idx];
          Cf[idx] = v;
        } else {
          ((u16*)C)[idx] = f2bf(v);
        }
      }
    }
  }
}

// ---------------------------------------------------------------------------
// Attention (R5 structure): O = softmax(Q Q^T / sqrt(S)) Q per (b,h).
// ---------------------------------------------------------------------------
__global__ __launch_bounds__(256) void attn_kernel(
    const u16* __restrict__ Q, const u16* __restrict__ Qt,
    u16* __restrict__ O) {
  __shared__ u16 KV[2][8192];
  __shared__ __align__(16) u16 Ps[4][2304];
  const int tid = threadIdx.x;
  const int w = tid >> 6, l = tid & 63;
  const int l16 = l & 15, kgrp = l >> 4;
  const int bh = blockIdx.y, b = bh >> 4, h = bh & 15;
  const int q0 = blockIdx.x * 128;
  const size_t rowQ = (size_t)(b * 2048 + q0 + w * 32);
  const float cexp = 1.4426950408889634f / 45.254833995939045f;

  const int srow = w * 8 + (l >> 3);
  const int sch8 = 8 * ((l & 7) ^ (srow & 7));
  const u16* gK0 = Q + (size_t)(b * 2048 + srow) * 1024 + h * 64 + sch8;
  const u16* gK1 = gK0 + (size_t)32 * 1024;
  const u16* gV0 = Qt + (size_t)(h * 64 + srow) * 4096 + b * 2048 + sch8;
  const u16* gV1 = gV0 + (size_t)32 * 4096;

  v8s qb[2][2];
#pragma unroll
  for (int nj = 0; nj < 2; nj++)
#pragma unroll
    for (int ks = 0; ks < 2; ks++) {
      v8s t = *(const v8s*)(Q + (rowQ + nj * 16 + l16) * 1024 + h * 64 + ks * 32 + kgrp * 8);
#pragma unroll
      for (int j = 0; j < 8; j++) t[j] = (short)f2bf(bf2f((u16)t[j]) * cexp);
      qb[nj][ks] = t;
    }

  v4f o[2][4];
  float ls[2] = {0.f, 0.f};
#pragma unroll
  for (int i = 0; i < 2; i++)
#pragma unroll
    for (int j = 0; j < 4; j++)
#pragma unroll
      for (int r = 0; r < 4; r++) o[i][j][r] = 0.f;

  gl_lds16(gK0, &KV[0][w * 512]);
  gl_lds16(gK1, &KV[0][2048 + w * 512]);
  gl_lds16(gV0, &KV[0][4096 + w * 512]);
  gl_lds16(gV1, &KV[0][4096 + 2048 + w * 512]);

  u16* Pw = &Ps[w][0];
  int cur = 0;
  for (int kb = 0; kb < 2048; kb += 64) {
    __syncthreads();
    if (kb + 64 < 2048) {
      int nxt = cur ^ 1;
      gl_lds16(gK0 + (size_t)(kb + 64) * 1024, &KV[nxt][w * 512]);
      gl_lds16(gK1 + (size_t)(kb + 64) * 1024, &KV[nxt][2048 + w * 512]);
      gl_lds16(gV0 + (kb + 64), &KV[nxt][4096 + w * 512]);
      gl_lds16(gV1 + (kb + 64), &KV[nxt][4096 + 2048 + w * 512]);
    }
    const u16* Ks = &KV[cur][0];
    const u16* Vt = &KV[cur][4096];

    v4f st[4][2];
#pragma unroll
    for (int i = 0; i < 4; i++)
#pragma unroll
      for (int j = 0; j < 2; j++)
#pragma unroll
        for (int r = 0; r < 4; r++) st[i][j][r] = 0.f;
#pragma unroll
    for (int ks = 0; ks < 2; ks++) {
      v8s ka[4];
#pragma unroll
      for (int mi = 0; mi < 4; mi++)
        ka[mi] = *(const v8s*)(Ks + (mi * 16 + l16) * 64 + 8 * ((ks * 4 + kgrp) ^ (l16 & 7)));
#pragma unroll
      for (int mi = 0; mi < 4; mi++)
#pragma unroll
        for (int nj = 0; nj < 2; nj++)
          st[mi][nj] = __builtin_amdgcn_mfma_f32_16x16x32_bf16(ka[mi], qb[nj][ks], st[mi][nj], 0, 0, 0);
    }

#pragma unroll
    for (int mi = 0; mi < 4; mi++)
#pragma unroll
      for (int nj = 0; nj < 2; nj++) {
        float p0 = __builtin_amdgcn_exp2f(st[mi][nj][0]);
        float p1 = __builtin_amdgcn_exp2f(st[mi][nj][1]);
        float p2 = __builtin_amdgcn_exp2f(st[mi][nj][2]);
        float p3 = __builtin_amdgcn_exp2f(st[mi][nj][3]);
        ls[nj] += (p0 + p1) + (p2 + p3);
        uint2 pk;
        pk.x = __builtin_amdgcn_perm(fbits(p1), fbits(p0), 0x07060302u);
        pk.y = __builtin_amdgcn_perm(fbits(p3), fbits(p2), 0x07060302u);
        *(uint2*)(Pw + (nj * 16 + l16) * 72 + mi * 16 + kgrp * 4) = pk;
      }

#pragma unroll
    for (int t = 0; t < 2; t++) {
      v8s pa[2], vb[4];
#pragma unroll
      for (int nj = 0; nj < 2; nj++)
        pa[nj] = *(const v8s*)(Pw + (nj * 16 + l16) * 72 + t * 32 + kgrp * 8);
#pragma unroll
      for (int ni = 0; ni < 4; ni++)
        vb[ni] = *(const v8s*)(Vt + (ni * 16 + l16) * 64 + 8 * ((t * 4 + kgrp) ^ (l16 & 7)));
#pragma unroll
      for (int nj = 0; nj < 2; nj++)
#pragma unroll
        for (int ni = 0; ni < 4; ni++)
          o[nj][ni] = __builtin_amdgcn_mfma_f32_16x16x32_bf16(pa[nj], vb[ni], o[nj][ni], 0, 0, 0);
    }
    cur ^= 1;
  }

#pragma unroll
  for (int nj = 0; nj < 2; nj++) {
    float t = ls[nj];
    t += __shfl_xor(t, 16, 64);
    t += __shfl_xor(t, 32, 64);
    ls[nj] = t;
  }

#pragma unroll
  for (int nj = 0; nj < 2; nj++) {
#pragma unroll
    for (int r = 0; r < 4; r++) {
      float den = __shfl(ls[nj], kgrp * 4 + r, 64);
      float rden = 1.f / den;
#pragma unroll
      for (int ni = 0; ni < 4; ni++) {
        O[(rowQ + nj * 16 + kgrp * 4 + r) * 1024 + h * 64 + ni * 16 + l16] =
            f2bf(o[nj][ni][r] * rden);
      }
    }
  }
}

// ---------------------------------------------------------------------------
// out = LayerNorm(Y [+ Y2 + Y3 + Y4] + Xr) * g + b; row length 1024; dtype
// flags (1 = fp32, 0 = bf16). Y2/Y3/Y4 nullable (Y3/Y4 always bf16).
// In-place safe.
// ---------------------------------------------------------------------------
__global__ __launch_bounds__(256) void ln_residual(
    const void* __restrict__ Y, const void* __restrict__ Y2,
    const void* __restrict__ Y3, const void* __restrict__ Y4,
    const void* __restrict__ Xr,
    const float* __restrict__ g, const float* __restrict__ bb,
    void* __restrict__ out, int yf, int y2f, int xf, int of) {
  const int row = blockIdx.x, tid = threadIdx.x;
  const size_t base = (size_t)row * 1024;
  float v[4], s = 0.f, sq = 0.f;
#pragma unroll
  for (int i = 0; i < 4; i++) {
    int c = tid + i * 256;
    float ya = yf ? ((const float*)Y)[base + c] : bf2f(((const u16*)Y)[base + c]);
    float xa = xf ? ((const float*)Xr)[base + c] : bf2f(((const u16*)Xr)[base + c]);
    float x = ya + xa;
    if (Y2) {
      float y2a = y2f ? ((const float*)Y2)[base + c] : bf2f(((const u16*)Y2)[base + c]);
      x += y2a;
    }
    if (Y3) x += bf2f(((const u16*)Y3)[base + c]);
    if (Y4) x += bf2f(((const u16*)Y4)[base + c]);
    v[i] = x; s += x; sq += x * x;
  }
#pragma unroll
  for (int off = 32; off >= 1; off >>= 1) {
    s += __shfl_down(s, off, 64);
    sq += __shfl_down(sq, off, 64);
  }
  __shared__ float rs[4], rq[4];
  const int w = tid >> 6, l = tid & 63;
  if (l == 0) { rs[w] = s; rq[w] = sq; }
  __syncthreads();
  s = rs[0] + rs[1] + rs[2] + rs[3];
  sq = rq[0] + rq[1] + rq[2] + rq[3];
  const float mu = s * (1.f / 1024.f);
  const float var = sq * (1.f / 1024.f) - mu * mu;
  const float rstd = rsqrtf(var + 1e-5f);
#pragma unroll
  for (int i = 0; i < 4; i++) {
    int c = tid + i * 256;
    float r = (v[i] - mu) * rstd * g[c] + bb[c];
    if (of) ((float*)out)[base + c] = r;
    else ((u16*)out)[base + c] = f2bf(r);
  }
}

// ---------------------------------------------------------------------------
extern "C" void kernel_launch(void* const* d_in, const int* in_sizes, int n_in,
                              void* d_out, int out_size, void* d_ws, size_t ws_size,
                              hipStream_t stream) {
  const float* x   = (const float*)d_in[0];
  const float* Wq  = (const float*)d_in[1];
  const float* bq  = (const float*)d_in[2];
  const float* Wo  = (const float*)d_in[3];
  const float* bo  = (const float*)d_in[4];
  const float* g1  = (const float*)d_in[5];
  const float* be1 = (const float*)d_in[6];
  const float* W1  = (const float*)d_in[7];
  const float* b1  = (const float*)d_in[8];
  const float* W2  = (const float*)d_in[9];
  const float* b2  = (const float*)d_in[10];
  const float* g2  = (const float*)d_in[11];
  const float* be2 = (const float*)d_in[12];
  float* out = (float*)d_out;
  u16* ws  = (u16*)d_ws;

  const size_t M1 = 1048576;
  dim3 blk(256);
  dim3 blk8(512);
  const bool big = ws_size >= (size_t)37 * M1 * 2;  // 74 MiB

  if (big) {
    u16* xb   = ws + 0;          // [0..4M)  -> attn -> P2_ffn2
    u16* Qb   = ws + 4 * M1;     // [4..8M)  -> x1
    u16* Qt   = ws + 8 * M1;     // [8..12M) -> Yb (Wo P0) -> P1_ffn2
    u16* WqT  = ws + 12 * M1;    // [12..13M) -> WoT
    u16* W1T  = ws + 13 * M1;    // [13..17M) P1_wo -> W1T -> P3_ffn2
    u16* W2T  = ws + 17 * M1;    // [17..21M) P2_wo -> W2T
    u16* Hh   = ws + 21 * M1;    // [21..37M) P3_wo (head) -> Hh
    u16* attn = xb;  u16* Yb = Qt;  u16* x1 = Qb;  u16* WoT = WqT;
    // Wo split-4 partials: dead regions until later writers run (all after LN1)
    u16* P1wo = W1T;             // overwritten by transpose(W1) after LN1
    u16* P2wo = W2T;             // overwritten by transpose(W2) after FFN1
    u16* P3wo = Hh;              // overwritten by FFN1 after LN1
    // FFN2 split-4 partials: dead after their last reads
    u16* P1f2 = Qt;              // Yb dead after LN1
    u16* P2f2 = xb;              // attn dead after Wo-proj
    u16* P3f2 = W1T;             // W1T dead after FFN1

    cvt_f2b<<<dim3(4096), blk, 0, stream>>>(x, xb, 1048576);
    transpose_f2b<<<dim3(32, 32), blk, 0, stream>>>(Wq, WqT, 1024, 1024, 1024, 1024);
    gemm_g2<<<dim3(16, 32), blk, 0, stream>>>(xb, WqT, bq, Qb, 4096, 1024, 1024, 0, 0, 0);

    transpose_b2b<<<dim3(32, 128), blk, 0, stream>>>(Qb, Qt, 4096, 1024, 1024, 4096);
    attn_kernel<<<dim3(16, 32), blk, 0, stream>>>(Qb, Qt, attn);

    // Wo projection: split-K=4 phase-pipelined 256x256, P0 -> Yb (bf16, +bias)
    transpose_f2b<<<dim3(32, 32), blk, 0, stream>>>(Wo, WoT, 1024, 1024, 1024, 1024);
    gemm_8p<<<dim3(4, 16, 4), blk8, 0, stream>>>(attn, WoT, bo, Yb, P1wo, P2wo, P3wo,
                                                 4096, 1024, 1024, 256, 0, 0);
    ln_residual<<<dim3(4096), blk, 0, stream>>>(Yb, P1wo, P2wo, P3wo, x, g1, be1, x1,
                                                0, 0, 1, 0);

    // FFN1: full-K phase-pipelined 256x256 (grid 256 = 1 block/CU)
    transpose_f2b<<<dim3(128, 32), blk, 0, stream>>>(W1, W1T, 1024, 4096, 4096, 1024);
    gemm_8p<<<dim3(16, 16, 1), blk8, 0, stream>>>(x1, W1T, b1, Hh,
                                                  nullptr, nullptr, nullptr,
                                                  4096, 4096, 1024, 1024, 1, 0);

    // FFN2: split-K=4 phase-pipelined 256x256, P0 -> out (fp32, +bias)
    transpose_f2b<<<dim3(32, 128), blk, 0, stream>>>(W2, W2T, 4096, 1024, 1024, 4096);
    gemm_8p<<<dim3(4, 16, 4), blk8, 0, stream>>>(Hh, W2T, b2, out, P1f2, P2f2, P3f2,
                                                 4096, 1024, 4096, 1024, 0, 1);

    ln_residual<<<dim3(4096), blk, 0, stream>>>(out, P1f2, P2f2, P3f2, x1, g2, be2, out,
                                                1, 0, 0, 1);
  } else {
    u16* xb   = ws + 0;
    u16* Qb   = ws + 4 * M1;
    u16* Qt   = ws + 8 * M1;
    u16* attn = xb;  u16* Yb = Qt;  u16* x1 = Qb;  u16* Hc = xb;
    u16* Wt1  = ws + 12 * M1;
    u16* Wt2  = ws + 13 * M1;

    cvt_f2b<<<dim3(4096), blk, 0, stream>>>(x, xb, 1048576);
    transpose_f2b<<<dim3(32, 32), blk, 0, stream>>>(Wq, Wt1, 1024, 1024, 1024, 1024);
    gemm_g2<<<dim3(16, 32), blk, 0, stream>>>(xb, Wt1, bq, Qb, 4096, 1024, 1024, 0, 0, 0);

    transpose_b2b<<<dim3(32, 128), blk, 0, stream>>>(Qb, Qt, 4096, 1024, 1024, 4096);
    attn_kernel<<<dim3(16, 32), blk, 0, stream>>>(Qb, Qt, attn);

    transpose_f2b<<<dim3(32, 32), blk, 0, stream>>>(Wo, Wt2, 1024, 1024, 1024, 1024);
    gemm_g2<<<dim3(16, 32), blk, 0, stream>>>(attn, Wt2, bo, Yb, 4096, 1024, 1024, 0, 0, 0);
    ln_residual<<<dim3(4096), blk, 0, stream>>>(Yb, nullptr, nullptr, nullptr, x, g1, be1,
                                                x1, 0, 0, 1, 0);

    for (int c = 0; c < 4; c++) {
      transpose_f2b<<<dim3(32, 32), blk, 0, stream>>>(W1 + (size_t)c * 1024, Wt1,
                                                      1024, 1024, 4096, 1024);
      gemm_g2<<<dim3(16, 32), blk, 0, stream>>>(x1, Wt1, b1 + (size_t)c * 1024, Hc,
                                                4096, 1024, 1024, 1, 0, 0);
      transpose_f2b<<<dim3(32, 32), blk, 0, stream>>>(W2 + (size_t)c * M1, Wt2,
                                                      1024, 1024, 1024, 1024);
      gemm_g2<<<dim3(16, 32), blk, 0, stream>>>(Hc, Wt2, (c == 0) ? b2 : (const float*)nullptr,
                                                out, 4096, 1024, 1024, 0, (c > 0) ? 1 : 0, 1);
    }
    ln_residual<<<dim3(4096), blk, 0, stream>>>(out, nullptr, nullptr, nullptr, x1, g2, be2,
                                                out, 1, 0, 0, 1);
  }
}

// Round 4
// 341.723 us; speedup vs baseline: 1.1226x; 1.0171x over previous
//
#include <hip/hip_runtime.h>
#include <stdint.h>

// B=2, S=2048, D=1024, H=16, DK=64, DH=4096. I/O fp32; internals bf16 MFMA.
// R11: attention rebuilt as 8-wave blocks (512 thr). Each wave owns 16 Q-rows
// (was 32): half the per-wave serial chain, 2x waves/SIMD (2->4) for latency
// hiding. Same LDS (50KB), same traffic, grid 512 = 2 blocks/CU exactly.
// GEMMs: phase-pipelined 256x256/BK=64 (gemm_8p, counted vmcnt) from R10.

typedef unsigned short u16;
typedef __attribute__((ext_vector_type(8))) short v8s;   // 8 x bf16
typedef __attribute__((ext_vector_type(4))) float v4f;

#define AS1 __attribute__((address_space(1)))
#define AS3 __attribute__((address_space(3)))

__device__ __forceinline__ void gl_lds16(const u16* g, u16* l) {
  __builtin_amdgcn_global_load_lds((const AS1 void*)g, (AS3 void*)l, 16, 0, 0);
}

__device__ __forceinline__ float bf2f(u16 u) {
  union { uint32_t i; float f; } v; v.i = ((uint32_t)u) << 16; return v.f;
}
__device__ __forceinline__ u16 f2bf(float f) {
  union { float f; uint32_t i; } v; v.f = f;
  uint32_t x = v.i;
  return (u16)((x + 0x7FFFu + ((x >> 16) & 1u)) >> 16);  // RNE
}
__device__ __forceinline__ uint32_t fbits(float f) {
  union { float f; uint32_t u; } v; v.f = f; return v.u;
}

// ---------------------------------------------------------------------------
__global__ __launch_bounds__(256) void cvt_f2b(
    const float* __restrict__ src, u16* __restrict__ dst, int n4) {
  int i = (blockIdx.x * 256 + threadIdx.x);
  if (i < n4) {
    float4 v = *(const float4*)(src + (size_t)i * 4);
    ushort4 o;
    o.x = f2bf(v.x); o.y = f2bf(v.y); o.z = f2bf(v.z); o.w = f2bf(v.w);
    *(ushort4*)(dst + (size_t)i * 4) = o;
  }
}

// ---------------------------------------------------------------------------
__global__ __launch_bounds__(256) void transpose_f2b(
    const float* __restrict__ src, u16* __restrict__ dst,
    int R, int C, int ld_s, int ld_d) {
  __shared__ float tile[32][33];
  const int tx = threadIdx.x & 31, ty = threadIdx.x >> 5;
  const int c0 = blockIdx.x * 32, r0 = blockIdx.y * 32;
#pragma unroll
  for (int j = 0; j < 32; j += 8)
    tile[ty + j][tx] = src[(size_t)(r0 + ty + j) * ld_s + c0 + tx];
  __syncthreads();
#pragma unroll
  for (int j = 0; j < 32; j += 8)
    dst[(size_t)(c0 + ty + j) * ld_d + r0 + tx] = f2bf(tile[tx][ty + j]);
}

__global__ __launch_bounds__(256) void transpose_b2b(
    const u16* __restrict__ src, u16* __restrict__ dst,
    int R, int C, int ld_s, int ld_d) {
  __shared__ u16 tile[32][33];
  const int tx = threadIdx.x & 31, ty = threadIdx.x >> 5;
  const int c0 = blockIdx.x * 32, r0 = blockIdx.y * 32;
#pragma unroll
  for (int j = 0; j < 32; j += 8)
    tile[ty + j][tx] = src[(size_t)(r0 + ty + j) * ld_s + c0 + tx];
  __syncthreads();
#pragma unroll
  for (int j = 0; j < 32; j += 8)
    dst[(size_t)(c0 + ty + j) * ld_d + r0 + tx] = tile[tx][ty + j];
}

// ---------------------------------------------------------------------------
// gemm_8p: 256x256 tile, BK=64, 512 threads (8 waves: 2M x 4N), 128 KiB LDS,
// phase-pipelined K-loop with counted vmcnt. blockIdx.z = K-split (klen per z).
// z==0 -> C0 (+bias, relu, fp32 or bf16); z=1..3 -> C1/C2/C3 bf16 partials.
// ---------------------------------------------------------------------------
__global__ __launch_bounds__(512, 1) void gemm_8p(
    const u16* __restrict__ A, const u16* __restrict__ Bt,
    const float* __restrict__ bias, void* __restrict__ C0,
    u16* __restrict__ C1, u16* __restrict__ C2, u16* __restrict__ C3,
    int M, int N, int ldk, int klen, int relu, int c0_f32) {
  __shared__ u16 As[2][16384];   // [buf][row*64 + elem], 256 rows x 64 k
  __shared__ u16 Bs[2][16384];
  const int tid = threadIdx.x;
  const int w = tid >> 6, l = tid & 63;
  const int l16 = l & 15, kgrp = (l >> 4) & 3;
  const int wm = w >> 2, wn = w & 3;
  const int m0 = blockIdx.y * 256, n0 = blockIdx.x * 256;
  const int z = blockIdx.z;
  const int NT = klen >> 6;

  const int rl = tid >> 3;
  const int sw = 8 * ((tid & 7) ^ (rl & 7));
  const u16* gA[4]; const u16* gB[4];
#pragma unroll
  for (int j = 0; j < 4; j++) {
    gA[j] = A + (size_t)(m0 + j * 64 + rl) * ldk + (size_t)z * klen + sw;
    gB[j] = Bt + (size_t)(n0 + j * 64 + rl) * ldk + (size_t)z * klen + sw;
  }
  const int sdst = w * 512;   // wave-uniform LDS base (+ j*4096)

  const int ch0 = 8 * ((kgrp) ^ (l16 & 7));
  const int ch1 = 8 * ((4 + kgrp) ^ (l16 & 7));
  const int abase = (wm * 128 + l16) * 64;
  const int bbase = (wn * 64 + l16) * 64;

  v4f acc[8][4];
#pragma unroll
  for (int i = 0; i < 8; i++)
#pragma unroll
    for (int j = 0; j < 4; j++)
#pragma unroll
      for (int r = 0; r < 4; r++) acc[i][j][r] = 0.f;

  v8s a[4][2], b[4][2];

#define FENCE() asm volatile("" ::: "memory")
#define VMC(n) asm volatile("s_waitcnt vmcnt(" #n ")" ::: "memory")
#define BARX() { __builtin_amdgcn_s_barrier(); \
                 __builtin_amdgcn_sched_barrier(0); FENCE(); }
#define STGA(q, j, kt) gl_lds16(gA[j] + (size_t)(kt) * 64, &As[q][(j) * 4096 + sdst])
#define STGB(q, j, kt) gl_lds16(gB[j] + (size_t)(kt) * 64, &Bs[q][(j) * 4096 + sdst])
#define LDA(p, mh) { \
  const u16* Ap = &As[p][abase + (mh) * 4096]; \
  _Pragma("unroll") for (int mi = 0; mi < 4; mi++) { \
    a[mi][0] = *(const v8s*)(Ap + mi * 1024 + ch0); \
    a[mi][1] = *(const v8s*)(Ap + mi * 1024 + ch1); } }
#define LDB(p, nh) { \
  const u16* Bp = &Bs[p][bbase + (nh) * 2048]; \
  _Pragma("unroll") for (int ni = 0; ni < 2; ni++) { \
    b[(nh) * 2 + ni][0] = *(const v8s*)(Bp + ni * 1024 + ch0); \
    b[(nh) * 2 + ni][1] = *(const v8s*)(Bp + ni * 1024 + ch1); } }
#define MFQ(mh, nh) { \
  __builtin_amdgcn_s_setprio(1); \
  _Pragma("unroll") for (int ks = 0; ks < 2; ks++) \
  _Pragma("unroll") for (int mi = 0; mi < 4; mi++) \
  _Pragma("unroll") for (int ni = 0; ni < 2; ni++) \
    acc[(mh) * 4 + mi][(nh) * 2 + ni] = __builtin_amdgcn_mfma_f32_16x16x32_bf16( \
        a[mi][ks], b[(nh) * 2 + ni][ks], acc[(mh) * 4 + mi][(nh) * 2 + ni], 0, 0, 0); \
  __builtin_amdgcn_s_setprio(0); }

  // prologue: stage tile 0 into buf0, need-first order: A02, B01, B23, A13
  STGA(0, 0, 0); STGA(0, 2, 0);
  FENCE();
  STGB(0, 0, 0); STGB(0, 1, 0);
  FENCE();
  STGB(0, 2, 0); STGB(0, 3, 0);
  FENCE();
  STGA(0, 1, 0); STGA(0, 3, 0);
  VMC(2); BARX();

  int p = 0;
  for (int kt = 0; kt < NT - 1; ++kt, p ^= 1) {
    const int q = p ^ 1;
    const int kn = kt + 1;
    // P1
    LDA(p, 0);
    LDB(p, 0);
    FENCE();
    STGA(q, 0, kn); STGA(q, 2, kn);
    MFQ(0, 0);
    // P2
    LDB(p, 1);
    FENCE();
    STGB(q, 0, kn); STGB(q, 1, kn);
    VMC(4); BARX();
    MFQ(0, 1);
    // P3
    LDA(p, 1);
    FENCE();
    STGB(q, 2, kn); STGB(q, 3, kn);
    MFQ(1, 1);
    // P4
    FENCE();
    STGA(q, 1, kn); STGA(q, 3, kn);
    VMC(2); BARX();
    MFQ(1, 0);
  }
  // peeled last tile
  VMC(0); BARX();
  LDA(p, 0);
  LDB(p, 0);
  MFQ(0, 0);
  LDB(p, 1);
  MFQ(0, 1);
  LDA(p, 1);
  MFQ(1, 1);
  MFQ(1, 0);

#undef FENCE
#undef VMC
#undef BARX
#undef STGA
#undef STGB
#undef LDA
#undef LDB
#undef MFQ

#pragma unroll
  for (int mi = 0; mi < 8; mi++) {
    const int row = m0 + wm * 128 + mi * 16 + kgrp * 4;
#pragma unroll
    for (int ni = 0; ni < 4; ni++) {
      const int col = n0 + wn * 64 + ni * 16 + l16;
      float bv = (bias && z == 0) ? bias[col] : 0.f;
#pragma unroll
      for (int r = 0; r < 4; r++) {
        float v = acc[mi][ni][r] + bv;
        if (z == 0 && relu) v = fmaxf(v, 0.f);
        size_t idx = (size_t)(row + r) * N + col;
        if (z == 0) {
          if (c0_f32) ((float*)C0)[idx] = v;
          else ((u16*)C0)[idx] = f2bf(v);
        } else if (z == 1) {
          C1[idx] = f2bf(v);
        } else if (z == 2) {
          C2[idx] = f2bf(v);
        } else {
          C3[idx] = f2bf(v);
        }
      }
    }
  }
}

// ---------------------------------------------------------------------------
// G2: 128x64 tile, BK=64, double-buffered (Qproj + small path).
// ---------------------------------------------------------------------------
__global__ __launch_bounds__(256) void gemm_g2(
    const u16* __restrict__ A, const u16* __restrict__ Bt,
    const float* __restrict__ bias, void* __restrict__ C,
    int M, int N, int K, int relu, int accum, int out_f32) {
  __shared__ u16 As[2][8192];
  __shared__ u16 Bs[2][4096];
  const int tid = threadIdx.x;
  const int w = tid >> 6, l = tid & 63;
  const int l16 = l & 15, kgrp = l >> 4;
  const int m0 = blockIdx.y * 128, n0 = blockIdx.x * 64;
  const int wr = (w >> 1) * 64, wc = (w & 1) * 32;

  const int srow = w * 8 + (l >> 3);
  const u16* gA[4];
#pragma unroll
  for (int i = 0; i < 4; i++) {
    int r = i * 32 + srow;
    gA[i] = A + (size_t)(m0 + r) * K + 8 * ((l & 7) ^ (r & 7));
  }
  const u16* gB[2];
#pragma unroll
  for (int i = 0; i < 2; i++) {
    int r = i * 32 + srow;
    gB[i] = Bt + (size_t)(n0 + r) * K + 8 * ((l & 7) ^ (r & 7));
  }

  v4f acc[4][2];
#pragma unroll
  for (int i = 0; i < 4; i++)
#pragma unroll
    for (int j = 0; j < 2; j++)
#pragma unroll
      for (int r = 0; r < 4; r++) acc[i][j][r] = 0.f;

#pragma unroll
  for (int i = 0; i < 4; i++) gl_lds16(gA[i], &As[0][(i * 256 + w * 64) * 8]);
#pragma unroll
  for (int i = 0; i < 2; i++) gl_lds16(gB[i], &Bs[0][(i * 256 + w * 64) * 8]);

  int cur = 0;
  for (int k0 = 0; k0 < K; k0 += 64) {
    __syncthreads();
    if (k0 + 64 < K) {
      int nxt = cur ^ 1;
#pragma unroll
      for (int i = 0; i < 4; i++)
        gl_lds16(gA[i] + k0 + 64, &As[nxt][(i * 256 + w * 64) * 8]);
#pragma unroll
      for (int i = 0; i < 2; i++)
        gl_lds16(gB[i] + k0 + 64, &Bs[nxt][(i * 256 + w * 64) * 8]);
    }
    v8s a[4][2], b[2][2];
#pragma unroll
    for (int ks = 0; ks < 2; ks++) {
      int ch = 8 * ((ks * 4 + kgrp) ^ (l16 & 7));
#pragma unroll
      for (int mi = 0; mi < 4; mi++)
        a[mi][ks] = *(const v8s*)(&As[cur][(wr + mi * 16 + l16) * 64 + ch]);
#pragma unroll
      for (int ni = 0; ni < 2; ni++)
        b[ni][ks] = *(const v8s*)(&Bs[cur][(wc + ni * 16 + l16) * 64 + ch]);
    }
#pragma unroll
    for (int ks = 0; ks < 2; ks++)
#pragma unroll
      for (int mi = 0; mi < 4; mi++)
#pragma unroll
        for (int ni = 0; ni < 2; ni++)
          acc[mi][ni] = __builtin_amdgcn_mfma_f32_16x16x32_bf16(a[mi][ks], b[ni][ks], acc[mi][ni], 0, 0, 0);
    cur ^= 1;
  }

#pragma unroll
  for (int ni = 0; ni < 2; ni++) {
    int col = n0 + wc + ni * 16 + l16;
    float bv = bias ? bias[col] : 0.f;
#pragma unroll
    for (int mi = 0; mi < 4; mi++) {
      int row = m0 + wr + mi * 16 + kgrp * 4;
#pragma unroll
      for (int r = 0; r < 4; r++) {
        float v = acc[mi][ni][r] + bv;
        if (relu) v = fmaxf(v, 0.f);
        size_t idx = (size_t)(row + r) * N + col;
        if (out_f32) {
          float* Cf = (float*)C;
          if (accum) v += Cf[idx];
          Cf[idx] = v;
        } else {
          ((u16*)C)[idx] = f2bf(v);
        }
      }
    }
  }
}

// ---------------------------------------------------------------------------
// Attention: O = softmax(Q Q^T / sqrt(S)) Q per (b,h).
// R11: 512 threads, 8 waves x 16 Q-rows. Grid (16, 32) = 512 blocks.
// LDS: KV dbuf 32KB + Ps 18KB = 50KB. Waves w<4 stage K (2x gl_lds16),
// w>=4 stage V. Same XOR swizzle invariant: chunk (l&7) ^ (row&7), row&7=l>>3.
// ---------------------------------------------------------------------------
__global__ __launch_bounds__(512) void attn_kernel(
    const u16* __restrict__ Q, const u16* __restrict__ Qt,
    u16* __restrict__ O) {
  __shared__ u16 KV[2][8192];
  __shared__ __align__(16) u16 Ps[8][1152];
  const int tid = threadIdx.x;
  const int w = tid >> 6, l = tid & 63;
  const int l16 = l & 15, kgrp = l >> 4;
  const int bh = blockIdx.y, b = bh >> 4, h = bh & 15;
  const int q0 = blockIdx.x * 128;
  const size_t rowQ = (size_t)(b * 2048 + q0 + w * 16);
  const float cexp = 1.4426950408889634f / 45.254833995939045f;

  // staging: wave w<4 stages K rows [16w .. 16w+15]; w>=4 stages V rows
  // (d-index) [16(w-4) .. +15]. Each wave: 2 loads of 8 rows (1 KB each).
  const int isV = w >> 2, wl = w & 3;
  const int r0 = wl * 16 + (l >> 3);
  const int sch8 = 8 * ((l & 7) ^ (l >> 3));
  const u16* gS0;
  size_t kstep;
  if (!isV) {
    gS0 = Q + (size_t)(b * 2048 + r0) * 1024 + h * 64 + sch8;
    kstep = 1024;
  } else {
    gS0 = Qt + (size_t)(h * 64 + r0) * 4096 + b * 2048 + sch8;
    kstep = 1;
  }
  const u16* gS1 = gS0 + (size_t)8 * (isV ? 4096 : 1024);
  const int ldst = isV * 4096 + wl * 1024;

  v8s qb[2];
#pragma unroll
  for (int ks = 0; ks < 2; ks++) {
    v8s t = *(const v8s*)(Q + (rowQ + l16) * 1024 + h * 64 + ks * 32 + kgrp * 8);
#pragma unroll
    for (int j = 0; j < 8; j++) t[j] = (short)f2bf(bf2f((u16)t[j]) * cexp);
    qb[ks] = t;
  }

  v4f o[4];
  float ls = 0.f;
#pragma unroll
  for (int j = 0; j < 4; j++)
#pragma unroll
    for (int r = 0; r < 4; r++) o[j][r] = 0.f;

  gl_lds16(gS0, &KV[0][ldst]);
  gl_lds16(gS1, &KV[0][ldst + 512]);

  u16* Pw = &Ps[w][0];
  int cur = 0;
  for (int kb = 0; kb < 2048; kb += 64) {
    __syncthreads();
    if (kb + 64 < 2048) {
      int nxt = cur ^ 1;
      gl_lds16(gS0 + (size_t)(kb + 64) * kstep, &KV[nxt][ldst]);
      gl_lds16(gS1 + (size_t)(kb + 64) * kstep, &KV[nxt][ldst + 512]);
    }
    const u16* Ks = &KV[cur][0];
    const u16* Vt = &KV[cur][4096];

    v4f st[4];
#pragma unroll
    for (int i = 0; i < 4; i++)
#pragma unroll
      for (int r = 0; r < 4; r++) st[i][r] = 0.f;
#pragma unroll
    for (int ks = 0; ks < 2; ks++) {
      v8s ka[4];
#pragma unroll
      for (int mi = 0; mi < 4; mi++)
        ka[mi] = *(const v8s*)(Ks + (mi * 16 + l16) * 64 + 8 * ((ks * 4 + kgrp) ^ (l16 & 7)));
#pragma unroll
      for (int mi = 0; mi < 4; mi++)
        st[mi] = __builtin_amdgcn_mfma_f32_16x16x32_bf16(ka[mi], qb[ks], st[mi], 0, 0, 0);
    }

#pragma unroll
    for (int mi = 0; mi < 4; mi++) {
      float p0 = __builtin_amdgcn_exp2f(st[mi][0]);
      float p1 = __builtin_amdgcn_exp2f(st[mi][1]);
      float p2 = __builtin_amdgcn_exp2f(st[mi][2]);
      float p3 = __builtin_amdgcn_exp2f(st[mi][3]);
      ls += (p0 + p1) + (p2 + p3);
      uint2 pk;
      pk.x = __builtin_amdgcn_perm(fbits(p1), fbits(p0), 0x07060302u);
      pk.y = __builtin_amdgcn_perm(fbits(p3), fbits(p2), 0x07060302u);
      *(uint2*)(Pw + l16 * 72 + mi * 16 + kgrp * 4) = pk;
    }

#pragma unroll
    for (int t = 0; t < 2; t++) {
      v8s pa, vb[4];
      pa = *(const v8s*)(Pw + l16 * 72 + t * 32 + kgrp * 8);
#pragma unroll
      for (int ni = 0; ni < 4; ni++)
        vb[ni] = *(const v8s*)(Vt + (ni * 16 + l16) * 64 + 8 * ((t * 4 + kgrp) ^ (l16 & 7)));
#pragma unroll
      for (int ni = 0; ni < 4; ni++)
        o[ni] = __builtin_amdgcn_mfma_f32_16x16x32_bf16(pa, vb[ni], o[ni], 0, 0, 0);
    }
    cur ^= 1;
  }

  {
    float t = ls;
    t += __shfl_xor(t, 16, 64);
    t += __shfl_xor(t, 32, 64);
    ls = t;
  }

#pragma unroll
  for (int r = 0; r < 4; r++) {
    float den = __shfl(ls, kgrp * 4 + r, 64);
    float rden = 1.f / den;
#pragma unroll
    for (int ni = 0; ni < 4; ni++) {
      O[(rowQ + kgrp * 4 + r) * 1024 + h * 64 + ni * 16 + l16] =
          f2bf(o[ni][r] * rden);
    }
  }
}

// ---------------------------------------------------------------------------
// out = LayerNorm(Y [+ Y2 + Y3 + Y4] + Xr) * g + b; row length 1024; dtype
// flags (1 = fp32, 0 = bf16). Y2/Y3/Y4 nullable (Y3/Y4 always bf16).
// In-place safe.
// ---------------------------------------------------------------------------
__global__ __launch_bounds__(256) void ln_residual(
    const void* __restrict__ Y, const void* __restrict__ Y2,
    const void* __restrict__ Y3, const void* __restrict__ Y4,
    const void* __restrict__ Xr,
    const float* __restrict__ g, const float* __restrict__ bb,
    void* __restrict__ out, int yf, int y2f, int xf, int of) {
  const int row = blockIdx.x, tid = threadIdx.x;
  const size_t base = (size_t)row * 1024;
  float v[4], s = 0.f, sq = 0.f;
#pragma unroll
  for (int i = 0; i < 4; i++) {
    int c = tid + i * 256;
    float ya = yf ? ((const float*)Y)[base + c] : bf2f(((const u16*)Y)[base + c]);
    float xa = xf ? ((const float*)Xr)[base + c] : bf2f(((const u16*)Xr)[base + c]);
    float x = ya + xa;
    if (Y2) {
      float y2a = y2f ? ((const float*)Y2)[base + c] : bf2f(((const u16*)Y2)[base + c]);
      x += y2a;
    }
    if (Y3) x += bf2f(((const u16*)Y3)[base + c]);
    if (Y4) x += bf2f(((const u16*)Y4)[base + c]);
    v[i] = x; s += x; sq += x * x;
  }
#pragma unroll
  for (int off = 32; off >= 1; off >>= 1) {
    s += __shfl_down(s, off, 64);
    sq += __shfl_down(sq, off, 64);
  }
  __shared__ float rs[4], rq[4];
  const int w = tid >> 6, l = tid & 63;
  if (l == 0) { rs[w] = s; rq[w] = sq; }
  __syncthreads();
  s = rs[0] + rs[1] + rs[2] + rs[3];
  sq = rq[0] + rq[1] + rq[2] + rq[3];
  const float mu = s * (1.f / 1024.f);
  const float var = sq * (1.f / 1024.f) - mu * mu;
  const float rstd = rsqrtf(var + 1e-5f);
#pragma unroll
  for (int i = 0; i < 4; i++) {
    int c = tid + i * 256;
    float r = (v[i] - mu) * rstd * g[c] + bb[c];
    if (of) ((float*)out)[base + c] = r;
    else ((u16*)out)[base + c] = f2bf(r);
  }
}

// ---------------------------------------------------------------------------
extern "C" void kernel_launch(void* const* d_in, const int* in_sizes, int n_in,
                              void* d_out, int out_size, void* d_ws, size_t ws_size,
                              hipStream_t stream) {
  const float* x   = (const float*)d_in[0];
  const float* Wq  = (const float*)d_in[1];
  const float* bq  = (const float*)d_in[2];
  const float* Wo  = (const float*)d_in[3];
  const float* bo  = (const float*)d_in[4];
  const float* g1  = (const float*)d_in[5];
  const float* be1 = (const float*)d_in[6];
  const float* W1  = (const float*)d_in[7];
  const float* b1  = (const float*)d_in[8];
  const float* W2  = (const float*)d_in[9];
  const float* b2  = (const float*)d_in[10];
  const float* g2  = (const float*)d_in[11];
  const float* be2 = (const float*)d_in[12];
  float* out = (float*)d_out;
  u16* ws  = (u16*)d_ws;

  const size_t M1 = 1048576;
  dim3 blk(256);
  dim3 blk8(512);
  const bool big = ws_size >= (size_t)37 * M1 * 2;  // 74 MiB

  if (big) {
    u16* xb   = ws + 0;          // [0..4M)  -> attn -> P2_ffn2
    u16* Qb   = ws + 4 * M1;     // [4..8M)  -> x1
    u16* Qt   = ws + 8 * M1;     // [8..12M) -> Yb (Wo P0) -> P1_ffn2
    u16* WqT  = ws + 12 * M1;    // [12..13M) -> WoT
    u16* W1T  = ws + 13 * M1;    // [13..17M) P1_wo -> W1T -> P3_ffn2
    u16* W2T  = ws + 17 * M1;    // [17..21M) P2_wo -> W2T
    u16* Hh   = ws + 21 * M1;    // [21..37M) P3_wo (head) -> Hh
    u16* attn = xb;  u16* Yb = Qt;  u16* x1 = Qb;  u16* WoT = WqT;
    // Wo split-4 partials: dead regions until later writers run (all after LN1)
    u16* P1wo = W1T;             // overwritten by transpose(W1) after LN1
    u16* P2wo = W2T;             // overwritten by transpose(W2) after FFN1
    u16* P3wo = Hh;              // overwritten by FFN1 after LN1
    // FFN2 split-4 partials: dead after their last reads
    u16* P1f2 = Qt;              // Yb dead after LN1
    u16* P2f2 = xb;              // attn dead after Wo-proj
    u16* P3f2 = W1T;             // W1T dead after FFN1

    cvt_f2b<<<dim3(4096), blk, 0, stream>>>(x, xb, 1048576);
    transpose_f2b<<<dim3(32, 32), blk, 0, stream>>>(Wq, WqT, 1024, 1024, 1024, 1024);
    gemm_g2<<<dim3(16, 32), blk, 0, stream>>>(xb, WqT, bq, Qb, 4096, 1024, 1024, 0, 0, 0);

    transpose_b2b<<<dim3(32, 128), blk, 0, stream>>>(Qb, Qt, 4096, 1024, 1024, 4096);
    attn_kernel<<<dim3(16, 32), blk8, 0, stream>>>(Qb, Qt, attn);

    // Wo projection: split-K=4 phase-pipelined 256x256, P0 -> Yb (bf16, +bias)
    transpose_f2b<<<dim3(32, 32), blk, 0, stream>>>(Wo, WoT, 1024, 1024, 1024, 1024);
    gemm_8p<<<dim3(4, 16, 4), blk8, 0, stream>>>(attn, WoT, bo, Yb, P1wo, P2wo, P3wo,
                                                 4096, 1024, 1024, 256, 0, 0);
    ln_residual<<<dim3(4096), blk, 0, stream>>>(Yb, P1wo, P2wo, P3wo, x, g1, be1, x1,
                                                0, 0, 1, 0);

    // FFN1: full-K phase-pipelined 256x256 (grid 256 = 1 block/CU)
    transpose_f2b<<<dim3(128, 32), blk, 0, stream>>>(W1, W1T, 1024, 4096, 4096, 1024);
    gemm_8p<<<dim3(16, 16, 1), blk8, 0, stream>>>(x1, W1T, b1, Hh,
                                                  nullptr, nullptr, nullptr,
                                                  4096, 4096, 1024, 1024, 1, 0);

    // FFN2: split-K=4 phase-pipelined 256x256, P0 -> out (fp32, +bias)
    transpose_f2b<<<dim3(32, 128), blk, 0, stream>>>(W2, W2T, 4096, 1024, 1024, 4096);
    gemm_8p<<<dim3(4, 16, 4), blk8, 0, stream>>>(Hh, W2T, b2, out, P1f2, P2f2, P3f2,
                                                 4096, 1024, 4096, 1024, 0, 1);

    ln_residual<<<dim3(4096), blk, 0, stream>>>(out, P1f2, P2f2, P3f2, x1, g2, be2, out,
                                                1, 0, 0, 1);
  } else {
    u16* xb   = ws + 0;
    u16* Qb   = ws + 4 * M1;
    u16* Qt   = ws + 8 * M1;
    u16* attn = xb;  u16* Yb = Qt;  u16* x1 = Qb;  u16* Hc = xb;
    u16* Wt1  = ws + 12 * M1;
    u16* Wt2  = ws + 13 * M1;

    cvt_f2b<<<dim3(4096), blk, 0, stream>>>(x, xb, 1048576);
    transpose_f2b<<<dim3(32, 32), blk, 0, stream>>>(Wq, Wt1, 1024, 1024, 1024, 1024);
    gemm_g2<<<dim3(16, 32), blk, 0, stream>>>(xb, Wt1, bq, Qb, 4096, 1024, 1024, 0, 0, 0);

    transpose_b2b<<<dim3(32, 128), blk, 0, stream>>>(Qb, Qt, 4096, 1024, 1024, 4096);
    attn_kernel<<<dim3(16, 32), blk8, 0, stream>>>(Qb, Qt, attn);

    transpose_f2b<<<dim3(32, 32), blk, 0, stream>>>(Wo, Wt2, 1024, 1024, 1024, 1024);
    gemm_g2<<<dim3(16, 32), blk, 0, stream>>>(attn, Wt2, bo, Yb, 4096, 1024, 1024, 0, 0, 0);
    ln_residual<<<dim3(4096), blk, 0, stream>>>(Yb, nullptr, nullptr, nullptr, x, g1, be1,
                                                x1, 0, 0, 1, 0);

    for (int c = 0; c < 4; c++) {
      transpose_f2b<<<dim3(32, 32), blk, 0, stream>>>(W1 + (size_t)c * 1024, Wt1,
                                                      1024, 1024, 4096, 1024);
      gemm_g2<<<dim3(16, 32), blk, 0, stream>>>(x1, Wt1, b1 + (size_t)c * 1024, Hc,
                                                4096, 1024, 1024, 1, 0, 0);
      transpose_f2b<<<dim3(32, 32), blk, 0, stream>>>(W2 + (size_t)c * M1, Wt2,
                                                      1024, 1024, 1024, 1024);
      gemm_g2<<<dim3(16, 32), blk, 0, stream>>>(Hc, Wt2, (c == 0) ? b2 : (const float*)nullptr,
                                                out, 4096, 1024, 1024, 0, (c > 0) ? 1 : 0, 1);
    }
    ln_residual<<<dim3(4096), blk, 0, stream>>>(out, nullptr, nullptr, nullptr, x1, g2, be2,
                                                out, 1, 0, 0, 1);
  }
}

// Round 5
// 339.801 us; speedup vs baseline: 1.1289x; 1.0057x over previous
//
#include <hip/hip_runtime.h>
#include <stdint.h>

// B=2, S=2048, D=1024, H=16, DK=64, DH=4096. I/O fp32; internals bf16 MFMA.
// R12: attention on 32x32x16 MFMA, 32 q-rows/wave, 8 waves (256-row blocks,
// grid 8x32=256). P kept fully in registers via perm-pack + permlane32_swap
// (no P LDS round-trip). LDS traffic 2.5x lower per unit work than R11
// (16KB/wave/tile for 32 rows vs 20KB for 16) -- R11 was LDS-BW-bound.
// GEMMs: phase-pipelined 256x256/BK=64 (gemm_8p, counted vmcnt) from R10.

typedef unsigned short u16;
typedef __attribute__((ext_vector_type(8))) short v8s;   // 8 x bf16
typedef __attribute__((ext_vector_type(4))) float v4f;
typedef __attribute__((ext_vector_type(16))) float v16f;
typedef __attribute__((ext_vector_type(2))) unsigned int v2u;

#define AS1 __attribute__((address_space(1)))
#define AS3 __attribute__((address_space(3)))

__device__ __forceinline__ void gl_lds16(const u16* g, u16* l) {
  __builtin_amdgcn_global_load_lds((const AS1 void*)g, (AS3 void*)l, 16, 0, 0);
}

__device__ __forceinline__ float bf2f(u16 u) {
  union { uint32_t i; float f; } v; v.i = ((uint32_t)u) << 16; return v.f;
}
__device__ __forceinline__ u16 f2bf(float f) {
  union { float f; uint32_t i; } v; v.f = f;
  uint32_t x = v.i;
  return (u16)((x + 0x7FFFu + ((x >> 16) & 1u)) >> 16);  // RNE
}
__device__ __forceinline__ uint32_t fbits(float f) {
  union { float f; uint32_t u; } v; v.f = f; return v.u;
}

// ---------------------------------------------------------------------------
__global__ __launch_bounds__(256) void cvt_f2b(
    const float* __restrict__ src, u16* __restrict__ dst, int n4) {
  int i = (blockIdx.x * 256 + threadIdx.x);
  if (i < n4) {
    float4 v = *(const float4*)(src + (size_t)i * 4);
    ushort4 o;
    o.x = f2bf(v.x); o.y = f2bf(v.y); o.z = f2bf(v.z); o.w = f2bf(v.w);
    *(ushort4*)(dst + (size_t)i * 4) = o;
  }
}

// ---------------------------------------------------------------------------
__global__ __launch_bounds__(256) void transpose_f2b(
    const float* __restrict__ src, u16* __restrict__ dst,
    int R, int C, int ld_s, int ld_d) {
  __shared__ float tile[32][33];
  const int tx = threadIdx.x & 31, ty = threadIdx.x >> 5;
  const int c0 = blockIdx.x * 32, r0 = blockIdx.y * 32;
#pragma unroll
  for (int j = 0; j < 32; j += 8)
    tile[ty + j][tx] = src[(size_t)(r0 + ty + j) * ld_s + c0 + tx];
  __syncthreads();
#pragma unroll
  for (int j = 0; j < 32; j += 8)
    dst[(size_t)(c0 + ty + j) * ld_d + r0 + tx] = f2bf(tile[tx][ty + j]);
}

__global__ __launch_bounds__(256) void transpose_b2b(
    const u16* __restrict__ src, u16* __restrict__ dst,
    int R, int C, int ld_s, int ld_d) {
  __shared__ u16 tile[32][33];
  const int tx = threadIdx.x & 31, ty = threadIdx.x >> 5;
  const int c0 = blockIdx.x * 32, r0 = blockIdx.y * 32;
#pragma unroll
  for (int j = 0; j < 32; j += 8)
    tile[ty + j][tx] = src[(size_t)(r0 + ty + j) * ld_s + c0 + tx];
  __syncthreads();
#pragma unroll
  for (int j = 0; j < 32; j += 8)
    dst[(size_t)(c0 + ty + j) * ld_d + r0 + tx] = tile[tx][ty + j];
}

// ---------------------------------------------------------------------------
// gemm_8p: 256x256 tile, BK=64, 512 threads (8 waves: 2M x 4N), 128 KiB LDS,
// phase-pipelined K-loop with counted vmcnt. blockIdx.z = K-split (klen per z).
// z==0 -> C0 (+bias, relu, fp32 or bf16); z=1..3 -> C1/C2/C3 bf16 partials.
// ---------------------------------------------------------------------------
__global__ __launch_bounds__(512, 1) void gemm_8p(
    const u16* __restrict__ A, const u16* __restrict__ Bt,
    const float* __restrict__ bias, void* __restrict__ C0,
    u16* __restrict__ C1, u16* __restrict__ C2, u16* __restrict__ C3,
    int M, int N, int ldk, int klen, int relu, int c0_f32) {
  __shared__ u16 As[2][16384];   // [buf][row*64 + elem], 256 rows x 64 k
  __shared__ u16 Bs[2][16384];
  const int tid = threadIdx.x;
  const int w = tid >> 6, l = tid & 63;
  const int l16 = l & 15, kgrp = (l >> 4) & 3;
  const int wm = w >> 2, wn = w & 3;
  const int m0 = blockIdx.y * 256, n0 = blockIdx.x * 256;
  const int z = blockIdx.z;
  const int NT = klen >> 6;

  const int rl = tid >> 3;
  const int sw = 8 * ((tid & 7) ^ (rl & 7));
  const u16* gA[4]; const u16* gB[4];
#pragma unroll
  for (int j = 0; j < 4; j++) {
    gA[j] = A + (size_t)(m0 + j * 64 + rl) * ldk + (size_t)z * klen + sw;
    gB[j] = Bt + (size_t)(n0 + j * 64 + rl) * ldk + (size_t)z * klen + sw;
  }
  const int sdst = w * 512;   // wave-uniform LDS base (+ j*4096)

  const int ch0 = 8 * ((kgrp) ^ (l16 & 7));
  const int ch1 = 8 * ((4 + kgrp) ^ (l16 & 7));
  const int abase = (wm * 128 + l16) * 64;
  const int bbase = (wn * 64 + l16) * 64;

  v4f acc[8][4];
#pragma unroll
  for (int i = 0; i < 8; i++)
#pragma unroll
    for (int j = 0; j < 4; j++)
#pragma unroll
      for (int r = 0; r < 4; r++) acc[i][j][r] = 0.f;

  v8s a[4][2], b[4][2];

#define FENCE() asm volatile("" ::: "memory")
#define VMC(n) asm volatile("s_waitcnt vmcnt(" #n ")" ::: "memory")
#define BARX() { __builtin_amdgcn_s_barrier(); \
                 __builtin_amdgcn_sched_barrier(0); FENCE(); }
#define STGA(q, j, kt) gl_lds16(gA[j] + (size_t)(kt) * 64, &As[q][(j) * 4096 + sdst])
#define STGB(q, j, kt) gl_lds16(gB[j] + (size_t)(kt) * 64, &Bs[q][(j) * 4096 + sdst])
#define LDA(p, mh) { \
  const u16* Ap = &As[p][abase + (mh) * 4096]; \
  _Pragma("unroll") for (int mi = 0; mi < 4; mi++) { \
    a[mi][0] = *(const v8s*)(Ap + mi * 1024 + ch0); \
    a[mi][1] = *(const v8s*)(Ap + mi * 1024 + ch1); } }
#define LDB(p, nh) { \
  const u16* Bp = &Bs[p][bbase + (nh) * 2048]; \
  _Pragma("unroll") for (int ni = 0; ni < 2; ni++) { \
    b[(nh) * 2 + ni][0] = *(const v8s*)(Bp + ni * 1024 + ch0); \
    b[(nh) * 2 + ni][1] = *(const v8s*)(Bp + ni * 1024 + ch1); } }
#define MFQ(mh, nh) { \
  __builtin_amdgcn_s_setprio(1); \
  _Pragma("unroll") for (int ks = 0; ks < 2; ks++) \
  _Pragma("unroll") for (int mi = 0; mi < 4; mi++) \
  _Pragma("unroll") for (int ni = 0; ni < 2; ni++) \
    acc[(mh) * 4 + mi][(nh) * 2 + ni] = __builtin_amdgcn_mfma_f32_16x16x32_bf16( \
        a[mi][ks], b[(nh) * 2 + ni][ks], acc[(mh) * 4 + mi][(nh) * 2 + ni], 0, 0, 0); \
  __builtin_amdgcn_s_setprio(0); }

  // prologue: stage tile 0 into buf0, need-first order: A02, B01, B23, A13
  STGA(0, 0, 0); STGA(0, 2, 0);
  FENCE();
  STGB(0, 0, 0); STGB(0, 1, 0);
  FENCE();
  STGB(0, 2, 0); STGB(0, 3, 0);
  FENCE();
  STGA(0, 1, 0); STGA(0, 3, 0);
  VMC(2); BARX();

  int p = 0;
  for (int kt = 0; kt < NT - 1; ++kt, p ^= 1) {
    const int q = p ^ 1;
    const int kn = kt + 1;
    // P1
    LDA(p, 0);
    LDB(p, 0);
    FENCE();
    STGA(q, 0, kn); STGA(q, 2, kn);
    MFQ(0, 0);
    // P2
    LDB(p, 1);
    FENCE();
    STGB(q, 0, kn); STGB(q, 1, kn);
    VMC(4); BARX();
    MFQ(0, 1);
    // P3
    LDA(p, 1);
    FENCE();
    STGB(q, 2, kn); STGB(q, 3, kn);
    MFQ(1, 1);
    // P4
    FENCE();
    STGA(q, 1, kn); STGA(q, 3, kn);
    VMC(2); BARX();
    MFQ(1, 0);
  }
  // peeled last tile
  VMC(0); BARX();
  LDA(p, 0);
  LDB(p, 0);
  MFQ(0, 0);
  LDB(p, 1);
  MFQ(0, 1);
  LDA(p, 1);
  MFQ(1, 1);
  MFQ(1, 0);

#undef FENCE
#undef VMC
#undef BARX
#undef STGA
#undef STGB
#undef LDA
#undef LDB
#undef MFQ

#pragma unroll
  for (int mi = 0; mi < 8; mi++) {
    const int row = m0 + wm * 128 + mi * 16 + kgrp * 4;
#pragma unroll
    for (int ni = 0; ni < 4; ni++) {
      const int col = n0 + wn * 64 + ni * 16 + l16;
      float bv = (bias && z == 0) ? bias[col] : 0.f;
#pragma unroll
      for (int r = 0; r < 4; r++) {
        float v = acc[mi][ni][r] + bv;
        if (z == 0 && relu) v = fmaxf(v, 0.f);
        size_t idx = (size_t)(row + r) * N + col;
        if (z == 0) {
          if (c0_f32) ((float*)C0)[idx] = v;
          else ((u16*)C0)[idx] = f2bf(v);
        } else if (z == 1) {
          C1[idx] = f2bf(v);
        } else if (z == 2) {
          C2[idx] = f2bf(v);
        } else {
          C3[idx] = f2bf(v);
        }
      }
    }
  }
}

// ---------------------------------------------------------------------------
// G2: 128x64 tile, BK=64, double-buffered (Qproj + small path).
// ---------------------------------------------------------------------------
__global__ __launch_bounds__(256) void gemm_g2(
    const u16* __restrict__ A, const u16* __restrict__ Bt,
    const float* __restrict__ bias, void* __restrict__ C,
    int M, int N, int K, int relu, int accum, int out_f32) {
  __shared__ u16 As[2][8192];
  __shared__ u16 Bs[2][4096];
  const int tid = threadIdx.x;
  const int w = tid >> 6, l = tid & 63;
  const int l16 = l & 15, kgrp = l >> 4;
  const int m0 = blockIdx.y * 128, n0 = blockIdx.x * 64;
  const int wr = (w >> 1) * 64, wc = (w & 1) * 32;

  const int srow = w * 8 + (l >> 3);
  const u16* gA[4];
#pragma unroll
  for (int i = 0; i < 4; i++) {
    int r = i * 32 + srow;
    gA[i] = A + (size_t)(m0 + r) * K + 8 * ((l & 7) ^ (r & 7));
  }
  const u16* gB[2];
#pragma unroll
  for (int i = 0; i < 2; i++) {
    int r = i * 32 + srow;
    gB[i] = Bt + (size_t)(n0 + r) * K + 8 * ((l & 7) ^ (r & 7));
  }

  v4f acc[4][2];
#pragma unroll
  for (int i = 0; i < 4; i++)
#pragma unroll
    for (int j = 0; j < 2; j++)
#pragma unroll
      for (int r = 0; r < 4; r++) acc[i][j][r] = 0.f;

#pragma unroll
  for (int i = 0; i < 4; i++) gl_lds16(gA[i], &As[0][(i * 256 + w * 64) * 8]);
#pragma unroll
  for (int i = 0; i < 2; i++) gl_lds16(gB[i], &Bs[0][(i * 256 + w * 64) * 8]);

  int cur = 0;
  for (int k0 = 0; k0 < K; k0 += 64) {
    __syncthreads();
    if (k0 + 64 < K) {
      int nxt = cur ^ 1;
#pragma unroll
      for (int i = 0; i < 4; i++)
        gl_lds16(gA[i] + k0 + 64, &As[nxt][(i * 256 + w * 64) * 8]);
#pragma unroll
      for (int i = 0; i < 2; i++)
        gl_lds16(gB[i] + k0 + 64, &Bs[nxt][(i * 256 + w * 64) * 8]);
    }
    v8s a[4][2], b[2][2];
#pragma unroll
    for (int ks = 0; ks < 2; ks++) {
      int ch = 8 * ((ks * 4 + kgrp) ^ (l16 & 7));
#pragma unroll
      for (int mi = 0; mi < 4; mi++)
        a[mi][ks] = *(const v8s*)(&As[cur][(wr + mi * 16 + l16) * 64 + ch]);
#pragma unroll
      for (int ni = 0; ni < 2; ni++)
        b[ni][ks] = *(const v8s*)(&Bs[cur][(wc + ni * 16 + l16) * 64 + ch]);
    }
#pragma unroll
    for (int ks = 0; ks < 2; ks++)
#pragma unroll
      for (int mi = 0; mi < 4; mi++)
#pragma unroll
        for (int ni = 0; ni < 2; ni++)
          acc[mi][ni] = __builtin_amdgcn_mfma_f32_16x16x32_bf16(a[mi][ks], b[ni][ks], acc[mi][ni], 0, 0, 0);
    cur ^= 1;
  }

#pragma unroll
  for (int ni = 0; ni < 2; ni++) {
    int col = n0 + wc + ni * 16 + l16;
    float bv = bias ? bias[col] : 0.f;
#pragma unroll
    for (int mi = 0; mi < 4; mi++) {
      int row = m0 + wr + mi * 16 + kgrp * 4;
#pragma unroll
      for (int r = 0; r < 4; r++) {
        float v = acc[mi][ni][r] + bv;
        if (relu) v = fmaxf(v, 0.f);
        size_t idx = (size_t)(row + r) * N + col;
        if (out_f32) {
          float* Cf = (float*)C;
          if (accum) v += Cf[idx];
          Cf[idx] = v;
        } else {
          ((u16*)C)[idx] = f2bf(v);
        }
      }
    }
  }
}

// ---------------------------------------------------------------------------
// Attention: O = softmax(Q Q^T / sqrt(S)) Q per (b,h).
// R12: 512 threads, 8 waves x 32 Q-rows (256-row blocks), 32x32x16 MFMA,
// P fully in-register (perm-pack + permlane32_swap). Grid (8, 32) = 256.
// LDS: KV dbuf 32KB only. Staging identical to R11 (w<4: K, w>=4: V).
//
// Layouts (32x32x16): A[row=l31][k=(l>>5)*8+j]; B[k=(l>>5)*8+j][col=l31];
// C/D: col=l31, row=(r&3)+8*(r>>2)+4*(l>>5).
// P redistribution per k-chunk t: reader (q,hi) needs P[q][16t+8hi+j];
// source = lane (q, j>>2), reg r = 4*(2(t&1)+hi)+(j&3), st-block kb=t>>1.
// permlane32_swap(dw_b0, dw_b1): out0 = [own b0 | partner b0],
// out1 = [partner b1 | own b1] -> exactly operand words (j<4 | j>=4).
// ---------------------------------------------------------------------------
__global__ __launch_bounds__(512) void attn_kernel(
    const u16* __restrict__ Q, const u16* __restrict__ Qt,
    u16* __restrict__ O) {
  __shared__ u16 KV[2][8192];
  const int tid = threadIdx.x;
  const int w = tid >> 6, l = tid & 63;
  const int l31 = l & 31, hi = l >> 5;
  const int bh = blockIdx.y, b = bh >> 4, h = bh & 15;
  const int q0 = blockIdx.x * 256;
  const size_t rowQ = (size_t)(b * 2048 + q0 + w * 32);
  const float cexp = 1.4426950408889634f / 45.254833995939045f;

  // staging: wave w<4 stages K rows [16w..16w+15]; w>=4 stages V d-rows.
  const int isV = w >> 2, wl = w & 3;
  const int r0 = wl * 16 + (l >> 3);
  const int sch8 = 8 * ((l & 7) ^ (l >> 3));
  const u16* gS0;
  size_t kstep;
  if (!isV) {
    gS0 = Q + (size_t)(b * 2048 + r0) * 1024 + h * 64 + sch8;
    kstep = 1024;
  } else {
    gS0 = Qt + (size_t)(h * 64 + r0) * 4096 + b * 2048 + sch8;
    kstep = 1;
  }
  const u16* gS1 = gS0 + (size_t)8 * (isV ? 4096 : 1024);
  const int ldst = isV * 4096 + wl * 1024;

  // Q fragments: qb[t] = Q[q=l31][d = 16t + 8*hi .. +7], pre-scaled.
  v8s qb[4];
#pragma unroll
  for (int t = 0; t < 4; t++) {
    v8s v = *(const v8s*)(Q + (rowQ + l31) * 1024 + h * 64 + t * 16 + hi * 8);
#pragma unroll
    for (int j = 0; j < 8; j++) v[j] = (short)f2bf(bf2f((u16)v[j]) * cexp);
    qb[t] = v;
  }

  v16f o0, o1;
#pragma unroll
  for (int r = 0; r < 16; r++) { o0[r] = 0.f; o1[r] = 0.f; }
  float ls = 0.f;

  gl_lds16(gS0, &KV[0][ldst]);
  gl_lds16(gS1, &KV[0][ldst + 512]);

  int cur = 0;
  for (int kb = 0; kb < 2048; kb += 64) {
    __syncthreads();
    if (kb + 64 < 2048) {
      int nxt = cur ^ 1;
      gl_lds16(gS0 + (size_t)(kb + 64) * kstep, &KV[nxt][ldst]);
      gl_lds16(gS1 + (size_t)(kb + 64) * kstep, &KV[nxt][ldst + 512]);
    }
    const u16* Ks = &KV[cur][0];
    const u16* Vt = &KV[cur][4096];

    // QK^T: S[krow][q], krow blocks 0-31 (s0) and 32-63 (s1)
    v16f s0, s1;
#pragma unroll
    for (int r = 0; r < 16; r++) { s0[r] = 0.f; s1[r] = 0.f; }
#pragma unroll
    for (int t = 0; t < 4; t++) {
      const int c = 8 * ((2 * t + hi) ^ (l & 7));
      v8s ka0 = *(const v8s*)(Ks + l31 * 64 + c);
      v8s ka1 = *(const v8s*)(Ks + (32 + l31) * 64 + c);
      s0 = __builtin_amdgcn_mfma_f32_32x32x16_bf16(ka0, qb[t], s0, 0, 0, 0);
      s1 = __builtin_amdgcn_mfma_f32_32x32x16_bf16(ka1, qb[t], s1, 0, 0, 0);
    }

    // exp (P values stay in registers)
    float p0[16], p1[16];
#pragma unroll
    for (int r = 0; r < 16; r++) {
      p0[r] = __builtin_amdgcn_exp2f(s0[r]);
      p1[r] = __builtin_amdgcn_exp2f(s1[r]);
      ls += p0[r] + p1[r];
    }

    // PV: 4 k-chunks of 16; P operand built via perm-pack + permlane32_swap.
#define PVSTEP(t, P) { \
      const int off = 8 * ((t) & 1); \
      uint32_t dw00 = __builtin_amdgcn_perm(fbits(P[off + 1]), fbits(P[off + 0]), 0x07060302u); \
      uint32_t dw01 = __builtin_amdgcn_perm(fbits(P[off + 3]), fbits(P[off + 2]), 0x07060302u); \
      uint32_t dw10 = __builtin_amdgcn_perm(fbits(P[off + 5]), fbits(P[off + 4]), 0x07060302u); \
      uint32_t dw11 = __builtin_amdgcn_perm(fbits(P[off + 7]), fbits(P[off + 6]), 0x07060302u); \
      v2u sA = __builtin_amdgcn_permlane32_swap(dw00, dw10, false, false); \
      v2u sB = __builtin_amdgcn_permlane32_swap(dw01, dw11, false, false); \
      union { uint32_t u[4]; v8s v; } pa; \
      pa.u[0] = sA[0]; pa.u[1] = sB[0]; pa.u[2] = sA[1]; pa.u[3] = sB[1]; \
      const int c = 8 * ((2 * (t) + hi) ^ (l & 7)); \
      v8s vb0 = *(const v8s*)(Vt + l31 * 64 + c); \
      v8s vb1 = *(const v8s*)(Vt + (32 + l31) * 64 + c); \
      o0 = __builtin_amdgcn_mfma_f32_32x32x16_bf16(pa.v, vb0, o0, 0, 0, 0); \
      o1 = __builtin_amdgcn_mfma_f32_32x32x16_bf16(pa.v, vb1, o1, 0, 0, 0); }
    PVSTEP(0, p0)
    PVSTEP(1, p0)
    PVSTEP(2, p1)
    PVSTEP(3, p1)
#undef PVSTEP
    cur ^= 1;
  }

  ls += __shfl_xor(ls, 32, 64);   // den[q] at lanes with l31 == q

  const int hiq = hi * 4;
#pragma unroll
  for (int r = 0; r < 16; r++) {
    const int qo = (r & 3) + 8 * (r >> 2) + hiq;
    float den = __shfl(ls, qo, 64);
    float rden = 1.f / den;
    O[(rowQ + qo) * 1024 + h * 64 + l31] = f2bf(o0[r] * rden);
    O[(rowQ + qo) * 1024 + h * 64 + 32 + l31] = f2bf(o1[r] * rden);
  }
}

// ---------------------------------------------------------------------------
// out = LayerNorm(Y [+ Y2 + Y3 + Y4] + Xr) * g + b; row length 1024; dtype
// flags (1 = fp32, 0 = bf16). Y2/Y3/Y4 nullable (Y3/Y4 always bf16).
// In-place safe.
// ---------------------------------------------------------------------------
__global__ __launch_bounds__(256) void ln_residual(
    const void* __restrict__ Y, const void* __restrict__ Y2,
    const void* __restrict__ Y3, const void* __restrict__ Y4,
    const void* __restrict__ Xr,
    const float* __restrict__ g, const float* __restrict__ bb,
    void* __restrict__ out, int yf, int y2f, int xf, int of) {
  const int row = blockIdx.x, tid = threadIdx.x;
  const size_t base = (size_t)row * 1024;
  float v[4], s = 0.f, sq = 0.f;
#pragma unroll
  for (int i = 0; i < 4; i++) {
    int c = tid + i * 256;
    float ya = yf ? ((const float*)Y)[base + c] : bf2f(((const u16*)Y)[base + c]);
    float xa = xf ? ((const float*)Xr)[base + c] : bf2f(((const u16*)Xr)[base + c]);
    float x = ya + xa;
    if (Y2) {
      float y2a = y2f ? ((const float*)Y2)[base + c] : bf2f(((const u16*)Y2)[base + c]);
      x += y2a;
    }
    if (Y3) x += bf2f(((const u16*)Y3)[base + c]);
    if (Y4) x += bf2f(((const u16*)Y4)[base + c]);
    v[i] = x; s += x; sq += x * x;
  }
#pragma unroll
  for (int off = 32; off >= 1; off >>= 1) {
    s += __shfl_down(s, off, 64);
    sq += __shfl_down(sq, off, 64);
  }
  __shared__ float rs[4], rq[4];
  const int w = tid >> 6, l = tid & 63;
  if (l == 0) { rs[w] = s; rq[w] = sq; }
  __syncthreads();
  s = rs[0] + rs[1] + rs[2] + rs[3];
  sq = rq[0] + rq[1] + rq[2] + rq[3];
  const float mu = s * (1.f / 1024.f);
  const float var = sq * (1.f / 1024.f) - mu * mu;
  const float rstd = rsqrtf(var + 1e-5f);
#pragma unroll
  for (int i = 0; i < 4; i++) {
    int c = tid + i * 256;
    float r = (v[i] - mu) * rstd * g[c] + bb[c];
    if (of) ((float*)out)[base + c] = r;
    else ((u16*)out)[base + c] = f2bf(r);
  }
}

// ---------------------------------------------------------------------------
extern "C" void kernel_launch(void* const* d_in, const int* in_sizes, int n_in,
                              void* d_out, int out_size, void* d_ws, size_t ws_size,
                              hipStream_t stream) {
  const float* x   = (const float*)d_in[0];
  const float* Wq  = (const float*)d_in[1];
  const float* bq  = (const float*)d_in[2];
  const float* Wo  = (const float*)d_in[3];
  const float* bo  = (const float*)d_in[4];
  const float* g1  = (const float*)d_in[5];
  const float* be1 = (const float*)d_in[6];
  const float* W1  = (const float*)d_in[7];
  const float* b1  = (const float*)d_in[8];
  const float* W2  = (const float*)d_in[9];
  const float* b2  = (const float*)d_in[10];
  const float* g2  = (const float*)d_in[11];
  const float* be2 = (const float*)d_in[12];
  float* out = (float*)d_out;
  u16* ws  = (u16*)d_ws;

  const size_t M1 = 1048576;
  dim3 blk(256);
  dim3 blk8(512);
  const bool big = ws_size >= (size_t)37 * M1 * 2;  // 74 MiB

  if (big) {
    u16* xb   = ws + 0;          // [0..4M)  -> attn -> P2_ffn2
    u16* Qb   = ws + 4 * M1;     // [4..8M)  -> x1
    u16* Qt   = ws + 8 * M1;     // [8..12M) -> Yb (Wo P0) -> P1_ffn2
    u16* WqT  = ws + 12 * M1;    // [12..13M) -> WoT
    u16* W1T  = ws + 13 * M1;    // [13..17M) P1_wo -> W1T -> P3_ffn2
    u16* W2T  = ws + 17 * M1;    // [17..21M) P2_wo -> W2T
    u16* Hh   = ws + 21 * M1;    // [21..37M) P3_wo (head) -> Hh
    u16* attn = xb;  u16* Yb = Qt;  u16* x1 = Qb;  u16* WoT = WqT;
    // Wo split-4 partials: dead regions until later writers run (all after LN1)
    u16* P1wo = W1T;             // overwritten by transpose(W1) after LN1
    u16* P2wo = W2T;             // overwritten by transpose(W2) after FFN1
    u16* P3wo = Hh;              // overwritten by FFN1 after LN1
    // FFN2 split-4 partials: dead after their last reads
    u16* P1f2 = Qt;              // Yb dead after LN1
    u16* P2f2 = xb;              // attn dead after Wo-proj
    u16* P3f2 = W1T;             // W1T dead after FFN1

    cvt_f2b<<<dim3(4096), blk, 0, stream>>>(x, xb, 1048576);
    transpose_f2b<<<dim3(32, 32), blk, 0, stream>>>(Wq, WqT, 1024, 1024, 1024, 1024);
    gemm_g2<<<dim3(16, 32), blk, 0, stream>>>(xb, WqT, bq, Qb, 4096, 1024, 1024, 0, 0, 0);

    transpose_b2b<<<dim3(32, 128), blk, 0, stream>>>(Qb, Qt, 4096, 1024, 1024, 4096);
    attn_kernel<<<dim3(8, 32), blk8, 0, stream>>>(Qb, Qt, attn);

    // Wo projection: split-K=4 phase-pipelined 256x256, P0 -> Yb (bf16, +bias)
    transpose_f2b<<<dim3(32, 32), blk, 0, stream>>>(Wo, WoT, 1024, 1024, 1024, 1024);
    gemm_8p<<<dim3(4, 16, 4), blk8, 0, stream>>>(attn, WoT, bo, Yb, P1wo, P2wo, P3wo,
                                                 4096, 1024, 1024, 256, 0, 0);
    ln_residual<<<dim3(4096), blk, 0, stream>>>(Yb, P1wo, P2wo, P3wo, x, g1, be1, x1,
                                                0, 0, 1, 0);

    // FFN1: full-K phase-pipelined 256x256 (grid 256 = 1 block/CU)
    transpose_f2b<<<dim3(128, 32), blk, 0, stream>>>(W1, W1T, 1024, 4096, 4096, 1024);
    gemm_8p<<<dim3(16, 16, 1), blk8, 0, stream>>>(x1, W1T, b1, Hh,
                                                  nullptr, nullptr, nullptr,
                                                  4096, 4096, 1024, 1024, 1, 0);

    // FFN2: split-K=4 phase-pipelined 256x256, P0 -> out (fp32, +bias)
    transpose_f2b<<<dim3(32, 128), blk, 0, stream>>>(W2, W2T, 4096, 1024, 1024, 4096);
    gemm_8p<<<dim3(4, 16, 4), blk8, 0, stream>>>(Hh, W2T, b2, out, P1f2, P2f2, P3f2,
                                                 4096, 1024, 4096, 1024, 0, 1);

    ln_residual<<<dim3(4096), blk, 0, stream>>>(out, P1f2, P2f2, P3f2, x1, g2, be2, out,
                                                1, 0, 0, 1);
  } else {
    u16* xb   = ws + 0;
    u16* Qb   = ws + 4 * M1;
    u16* Qt   = ws + 8 * M1;
    u16* attn = xb;  u16* Yb = Qt;  u16* x1 = Qb;  u16* Hc = xb;
    u16* Wt1  = ws + 12 * M1;
    u16* Wt2  = ws + 13 * M1;

    cvt_f2b<<<dim3(4096), blk, 0, stream>>>(x, xb, 1048576);
    transpose_f2b<<<dim3(32, 32), blk, 0, stream>>>(Wq, Wt1, 1024, 1024, 1024, 1024);
    gemm_g2<<<dim3(16, 32), blk, 0, stream>>>(xb, Wt1, bq, Qb, 4096, 1024, 1024, 0, 0, 0);

    transpose_b2b<<<dim3(32, 128), blk, 0, stream>>>(Qb, Qt, 4096, 1024, 1024, 4096);
    attn_kernel<<<dim3(8, 32), blk8, 0, stream>>>(Qb, Qt, attn);

    transpose_f2b<<<dim3(32, 32), blk, 0, stream>>>(Wo, Wt2, 1024, 1024, 1024, 1024);
    gemm_g2<<<dim3(16, 32), blk, 0, stream>>>(attn, Wt2, bo, Yb, 4096, 1024, 1024, 0, 0, 0);
    ln_residual<<<dim3(4096), blk, 0, stream>>>(Yb, nullptr, nullptr, nullptr, x, g1, be1,
                                                x1, 0, 0, 1, 0);

    for (int c = 0; c < 4; c++) {
      transpose_f2b<<<dim3(32, 32), blk, 0, stream>>>(W1 + (size_t)c * 1024, Wt1,
                                                      1024, 1024, 4096, 1024);
      gemm_g2<<<dim3(16, 32), blk, 0, stream>>>(x1, Wt1, b1 + (size_t)c * 1024, Hc,
                                                4096, 1024, 1024, 1, 0, 0);
      transpose_f2b<<<dim3(32, 32), blk, 0, stream>>>(W2 + (size_t)c * M1, Wt2,
                                                      1024, 1024, 1024, 1024);
      gemm_g2<<<dim3(16, 32), blk, 0, stream>>>(Hc, Wt2, (c == 0) ? b2 : (const float*)nullptr,
                                                out, 4096, 1024, 1024, 0, (c > 0) ? 1 : 0, 1);
    }
    ln_residual<<<dim3(4096), blk, 0, stream>>>(out, nullptr, nullptr, nullptr, x1, g2, be2,
                                                out, 1, 0, 0, 1);
  }
}

// Round 6
// 337.073 us; speedup vs baseline: 1.1381x; 1.0081x over previous
//
#include <hip/hip_runtime.h>
#include <stdint.h>

// B=2, S=2048, D=1024, H=16, DK=64, DH=4096. I/O fp32; internals bf16 MFMA.
// R13: gemm_8p upgraded to the full m201-style schedule: per-phase barrier
// pairs with lgkmcnt(0) lockstep (4 phases/K-tile, 16 MFMA each), counted
// vmcnt(4)/vmcnt(2) (never 0 in steady state), setprio around MFMA, and a
// bijective XCD-aware block swizzle (nwg%8==0 for all launches).
// Attention: R12 32x32 in-register-P version. Split-K=4 + LN-fold from R9.

typedef unsigned short u16;
typedef __attribute__((ext_vector_type(8))) short v8s;   // 8 x bf16
typedef __attribute__((ext_vector_type(4))) float v4f;
typedef __attribute__((ext_vector_type(16))) float v16f;
typedef __attribute__((ext_vector_type(2))) unsigned int v2u;

#define AS1 __attribute__((address_space(1)))
#define AS3 __attribute__((address_space(3)))

__device__ __forceinline__ void gl_lds16(const u16* g, u16* l) {
  __builtin_amdgcn_global_load_lds((const AS1 void*)g, (AS3 void*)l, 16, 0, 0);
}

__device__ __forceinline__ float bf2f(u16 u) {
  union { uint32_t i; float f; } v; v.i = ((uint32_t)u) << 16; return v.f;
}
__device__ __forceinline__ u16 f2bf(float f) {
  union { float f; uint32_t i; } v; v.f = f;
  uint32_t x = v.i;
  return (u16)((x + 0x7FFFu + ((x >> 16) & 1u)) >> 16);  // RNE
}
__device__ __forceinline__ uint32_t fbits(float f) {
  union { float f; uint32_t u; } v; v.f = f; return v.u;
}

// ---------------------------------------------------------------------------
__global__ __launch_bounds__(256) void cvt_f2b(
    const float* __restrict__ src, u16* __restrict__ dst, int n4) {
  int i = (blockIdx.x * 256 + threadIdx.x);
  if (i < n4) {
    float4 v = *(const float4*)(src + (size_t)i * 4);
    ushort4 o;
    o.x = f2bf(v.x); o.y = f2bf(v.y); o.z = f2bf(v.z); o.w = f2bf(v.w);
    *(ushort4*)(dst + (size_t)i * 4) = o;
  }
}

// ---------------------------------------------------------------------------
__global__ __launch_bounds__(256) void transpose_f2b(
    const float* __restrict__ src, u16* __restrict__ dst,
    int R, int C, int ld_s, int ld_d) {
  __shared__ float tile[32][33];
  const int tx = threadIdx.x & 31, ty = threadIdx.x >> 5;
  const int c0 = blockIdx.x * 32, r0 = blockIdx.y * 32;
#pragma unroll
  for (int j = 0; j < 32; j += 8)
    tile[ty + j][tx] = src[(size_t)(r0 + ty + j) * ld_s + c0 + tx];
  __syncthreads();
#pragma unroll
  for (int j = 0; j < 32; j += 8)
    dst[(size_t)(c0 + ty + j) * ld_d + r0 + tx] = f2bf(tile[tx][ty + j]);
}

__global__ __launch_bounds__(256) void transpose_b2b(
    const u16* __restrict__ src, u16* __restrict__ dst,
    int R, int C, int ld_s, int ld_d) {
  __shared__ u16 tile[32][33];
  const int tx = threadIdx.x & 31, ty = threadIdx.x >> 5;
  const int c0 = blockIdx.x * 32, r0 = blockIdx.y * 32;
#pragma unroll
  for (int j = 0; j < 32; j += 8)
    tile[ty + j][tx] = src[(size_t)(r0 + ty + j) * ld_s + c0 + tx];
  __syncthreads();
#pragma unroll
  for (int j = 0; j < 32; j += 8)
    dst[(size_t)(c0 + ty + j) * ld_d + r0 + tx] = tile[tx][ty + j];
}

// ---------------------------------------------------------------------------
// gemm_8p: 256x256 tile, BK=64, 512 threads (8 waves: 2M x 4N), 128 KiB LDS.
// m201-style 4-phase K-loop: each phase = [ds_read quadrant | stage pair] ->
// s_barrier -> lgkmcnt(0) -> setprio(1) 16 MFMA setprio(0) -> s_barrier.
// Counted vmcnt: VMC(4) end of Ph2 (retires A13(t) before Ph3 reads),
// VMC(2) end of Ph4 (retires A02/B01/B23(t+1) before next Ph1). Never 0 in
// steady state. blockIdx swizzled XCD-aware (bijective; nwg%8==0).
// z==0 -> C0 (+bias, relu, fp32 or bf16); z=1..3 -> C1/C2/C3 bf16 partials.
// ---------------------------------------------------------------------------
__global__ __launch_bounds__(512, 1) void gemm_8p(
    const u16* __restrict__ A, const u16* __restrict__ Bt,
    const float* __restrict__ bias, void* __restrict__ C0,
    u16* __restrict__ C1, u16* __restrict__ C2, u16* __restrict__ C3,
    int M, int N, int ldk, int klen, int relu, int c0_f32) {
  __shared__ u16 As[2][16384];   // [buf][row*64 + elem], 256 rows x 64 k
  __shared__ u16 Bs[2][16384];
  const int tid = threadIdx.x;
  const int w = tid >> 6, l = tid & 63;
  const int l16 = l & 15, kgrp = (l >> 4) & 3;
  const int wm = w >> 2, wn = w & 3;

  // XCD-aware bijective swizzle over full linear id (all launches nwg%8==0)
  const int gx = gridDim.x, gyd = gridDim.y;
  const int nxy = gx * gyd;
  const int nwg = nxy * gridDim.z;
  int lin = blockIdx.x + gx * (blockIdx.y + gyd * blockIdx.z);
  if ((nwg & 7) == 0) lin = (lin & 7) * (nwg >> 3) + (lin >> 3);
  const int z = lin / nxy;
  const int rem = lin - z * nxy;
  const int by = rem / gx;
  const int bx = rem - by * gx;
  const int m0 = by * 256, n0 = bx * 256;
  const int NT = klen >> 6;

  const int rl = tid >> 3;
  const int sw = 8 * ((tid & 7) ^ (rl & 7));
  const u16* gA[4]; const u16* gB[4];
#pragma unroll
  for (int j = 0; j < 4; j++) {
    gA[j] = A + (size_t)(m0 + j * 64 + rl) * ldk + (size_t)z * klen + sw;
    gB[j] = Bt + (size_t)(n0 + j * 64 + rl) * ldk + (size_t)z * klen + sw;
  }
  const int sdst = w * 512;   // wave-uniform LDS base (+ j*4096)

  const int ch0 = 8 * ((kgrp) ^ (l16 & 7));
  const int ch1 = 8 * ((4 + kgrp) ^ (l16 & 7));
  const int abase = (wm * 128 + l16) * 64;
  const int bbase = (wn * 64 + l16) * 64;

  v4f acc[8][4];
#pragma unroll
  for (int i = 0; i < 8; i++)
#pragma unroll
    for (int j = 0; j < 4; j++)
#pragma unroll
      for (int r = 0; r < 4; r++) acc[i][j][r] = 0.f;

  v8s a[4][2], b[4][2];

#define FENCE() asm volatile("" ::: "memory")
#define VMC(n) asm volatile("s_waitcnt vmcnt(" #n ")" ::: "memory")
#define LGKM0() { asm volatile("s_waitcnt lgkmcnt(0)" ::: "memory"); \
                  __builtin_amdgcn_sched_barrier(0); }
#define BARX() { __builtin_amdgcn_s_barrier(); \
                 __builtin_amdgcn_sched_barrier(0); FENCE(); }
#define STGA(q, j, kt) gl_lds16(gA[j] + (size_t)(kt) * 64, &As[q][(j) * 4096 + sdst])
#define STGB(q, j, kt) gl_lds16(gB[j] + (size_t)(kt) * 64, &Bs[q][(j) * 4096 + sdst])
#define LDA(p, mh) { \
  const u16* Ap = &As[p][abase + (mh) * 4096]; \
  _Pragma("unroll") for (int mi = 0; mi < 4; mi++) { \
    a[mi][0] = *(const v8s*)(Ap + mi * 1024 + ch0); \
    a[mi][1] = *(const v8s*)(Ap + mi * 1024 + ch1); } }
#define LDB(p, nh) { \
  const u16* Bp = &Bs[p][bbase + (nh) * 2048]; \
  _Pragma("unroll") for (int ni = 0; ni < 2; ni++) { \
    b[(nh) * 2 + ni][0] = *(const v8s*)(Bp + ni * 1024 + ch0); \
    b[(nh) * 2 + ni][1] = *(const v8s*)(Bp + ni * 1024 + ch1); } }
#define MFQ(mh, nh) { \
  __builtin_amdgcn_s_setprio(1); \
  _Pragma("unroll") for (int ks = 0; ks < 2; ks++) \
  _Pragma("unroll") for (int mi = 0; mi < 4; mi++) \
  _Pragma("unroll") for (int ni = 0; ni < 2; ni++) \
    acc[(mh) * 4 + mi][(nh) * 2 + ni] = __builtin_amdgcn_mfma_f32_16x16x32_bf16( \
        a[mi][ks], b[(nh) * 2 + ni][ks], acc[(mh) * 4 + mi][(nh) * 2 + ni], 0, 0, 0); \
  __builtin_amdgcn_s_setprio(0); }

  // prologue: stage tile 0 into buf0, need-first order: A02, B01, B23, A13
  STGA(0, 0, 0); STGA(0, 2, 0);
  FENCE();
  STGB(0, 0, 0); STGB(0, 1, 0);
  FENCE();
  STGB(0, 2, 0); STGB(0, 3, 0);
  FENCE();
  STGA(0, 1, 0); STGA(0, 3, 0);
  VMC(2); BARX();

  int p = 0;
  for (int kt = 0; kt < NT - 1; ++kt, p ^= 1) {
    const int q = p ^ 1;
    const int kn = kt + 1;
    // Ph1: read A-half0 + B-half0 of tile kt; stage A02 of kt+1
    LDA(p, 0);
    LDB(p, 0);
    FENCE();
    STGA(q, 0, kn); STGA(q, 2, kn);
    BARX(); LGKM0();
    MFQ(0, 0);
    BARX();
    // Ph2: read B-half1; stage B01 of kt+1; retire A13(kt)
    LDB(p, 1);
    FENCE();
    STGB(q, 0, kn); STGB(q, 1, kn);
    VMC(4);
    BARX(); LGKM0();
    MFQ(0, 1);
    BARX();
    // Ph3: read A-half1; stage B23 of kt+1
    LDA(p, 1);
    FENCE();
    STGB(q, 2, kn); STGB(q, 3, kn);
    BARX(); LGKM0();
    MFQ(1, 1);
    BARX();
    // Ph4: stage A13 of kt+1; retire A02/B01/B23(kt+1)
    FENCE();
    STGA(q, 1, kn); STGA(q, 3, kn);
    VMC(2);
    BARX(); LGKM0();
    MFQ(1, 0);
    BARX();
  }
  // peeled last tile: drain everything; no staging, no barriers.
  VMC(0); BARX();
  LDA(p, 0);
  LDB(p, 0);
  MFQ(0, 0);
  LDB(p, 1);
  MFQ(0, 1);
  LDA(p, 1);
  MFQ(1, 1);
  MFQ(1, 0);

#undef FENCE
#undef VMC
#undef LGKM0
#undef BARX
#undef STGA
#undef STGB
#undef LDA
#undef LDB
#undef MFQ

#pragma unroll
  for (int mi = 0; mi < 8; mi++) {
    const int row = m0 + wm * 128 + mi * 16 + kgrp * 4;
#pragma unroll
    for (int ni = 0; ni < 4; ni++) {
      const int col = n0 + wn * 64 + ni * 16 + l16;
      float bv = (bias && z == 0) ? bias[col] : 0.f;
#pragma unroll
      for (int r = 0; r < 4; r++) {
        float v = acc[mi][ni][r] + bv;
        if (z == 0 && relu) v = fmaxf(v, 0.f);
        size_t idx = (size_t)(row + r) * N + col;
        if (z == 0) {
          if (c0_f32) ((float*)C0)[idx] = v;
          else ((u16*)C0)[idx] = f2bf(v);
        } else if (z == 1) {
          C1[idx] = f2bf(v);
        } else if (z == 2) {
          C2[idx] = f2bf(v);
        } else {
          C3[idx] = f2bf(v);
        }
      }
    }
  }
}

// ---------------------------------------------------------------------------
// G2: 128x64 tile, BK=64, double-buffered (Qproj + small path).
// ---------------------------------------------------------------------------
__global__ __launch_bounds__(256) void gemm_g2(
    const u16* __restrict__ A, const u16* __restrict__ Bt,
    const float* __restrict__ bias, void* __restrict__ C,
    int M, int N, int K, int relu, int accum, int out_f32) {
  __shared__ u16 As[2][8192];
  __shared__ u16 Bs[2][4096];
  const int tid = threadIdx.x;
  const int w = tid >> 6, l = tid & 63;
  const int l16 = l & 15, kgrp = l >> 4;
  const int m0 = blockIdx.y * 128, n0 = blockIdx.x * 64;
  const int wr = (w >> 1) * 64, wc = (w & 1) * 32;

  const int srow = w * 8 + (l >> 3);
  const u16* gA[4];
#pragma unroll
  for (int i = 0; i < 4; i++) {
    int r = i * 32 + srow;
    gA[i] = A + (size_t)(m0 + r) * K + 8 * ((l & 7) ^ (r & 7));
  }
  const u16* gB[2];
#pragma unroll
  for (int i = 0; i < 2; i++) {
    int r = i * 32 + srow;
    gB[i] = Bt + (size_t)(n0 + r) * K + 8 * ((l & 7) ^ (r & 7));
  }

  v4f acc[4][2];
#pragma unroll
  for (int i = 0; i < 4; i++)
#pragma unroll
    for (int j = 0; j < 2; j++)
#pragma unroll
      for (int r = 0; r < 4; r++) acc[i][j][r] = 0.f;

#pragma unroll
  for (int i = 0; i < 4; i++) gl_lds16(gA[i], &As[0][(i * 256 + w * 64) * 8]);
#pragma unroll
  for (int i = 0; i < 2; i++) gl_lds16(gB[i], &Bs[0][(i * 256 + w * 64) * 8]);

  int cur = 0;
  for (int k0 = 0; k0 < K; k0 += 64) {
    __syncthreads();
    if (k0 + 64 < K) {
      int nxt = cur ^ 1;
#pragma unroll
      for (int i = 0; i < 4; i++)
        gl_lds16(gA[i] + k0 + 64, &As[nxt][(i * 256 + w * 64) * 8]);
#pragma unroll
      for (int i = 0; i < 2; i++)
        gl_lds16(gB[i] + k0 + 64, &Bs[nxt][(i * 256 + w * 64) * 8]);
    }
    v8s a[4][2], b[2][2];
#pragma unroll
    for (int ks = 0; ks < 2; ks++) {
      int ch = 8 * ((ks * 4 + kgrp) ^ (l16 & 7));
#pragma unroll
      for (int mi = 0; mi < 4; mi++)
        a[mi][ks] = *(const v8s*)(&As[cur][(wr + mi * 16 + l16) * 64 + ch]);
#pragma unroll
      for (int ni = 0; ni < 2; ni++)
        b[ni][ks] = *(const v8s*)(&Bs[cur][(wc + ni * 16 + l16) * 64 + ch]);
    }
#pragma unroll
    for (int ks = 0; ks < 2; ks++)
#pragma unroll
      for (int mi = 0; mi < 4; mi++)
#pragma unroll
        for (int ni = 0; ni < 2; ni++)
          acc[mi][ni] = __builtin_amdgcn_mfma_f32_16x16x32_bf16(a[mi][ks], b[ni][ks], acc[mi][ni], 0, 0, 0);
    cur ^= 1;
  }

#pragma unroll
  for (int ni = 0; ni < 2; ni++) {
    int col = n0 + wc + ni * 16 + l16;
    float bv = bias ? bias[col] : 0.f;
#pragma unroll
    for (int mi = 0; mi < 4; mi++) {
      int row = m0 + wr + mi * 16 + kgrp * 4;
#pragma unroll
      for (int r = 0; r < 4; r++) {
        float v = acc[mi][ni][r] + bv;
        if (relu) v = fmaxf(v, 0.f);
        size_t idx = (size_t)(row + r) * N + col;
        if (out_f32) {
          float* Cf = (float*)C;
          if (accum) v += Cf[idx];
          Cf[idx] = v;
        } else {
          ((u16*)C)[idx] = f2bf(v);
        }
      }
    }
  }
}

// ---------------------------------------------------------------------------
// Attention: O = softmax(Q Q^T / sqrt(S)) Q per (b,h).
// R12: 512 threads, 8 waves x 32 Q-rows (256-row blocks), 32x32x16 MFMA,
// P fully in-register (perm-pack + permlane32_swap). Grid (8, 32) = 256.
// ---------------------------------------------------------------------------
__global__ __launch_bounds__(512) void attn_kernel(
    const u16* __restrict__ Q, const u16* __restrict__ Qt,
    u16* __restrict__ O) {
  __shared__ u16 KV[2][8192];
  const int tid = threadIdx.x;
  const int w = tid >> 6, l = tid & 63;
  const int l31 = l & 31, hi = l >> 5;
  const int bh = blockIdx.y, b = bh >> 4, h = bh & 15;
  const int q0 = blockIdx.x * 256;
  const size_t rowQ = (size_t)(b * 2048 + q0 + w * 32);
  const float cexp = 1.4426950408889634f / 45.254833995939045f;

  const int isV = w >> 2, wl = w & 3;
  const int r0 = wl * 16 + (l >> 3);
  const int sch8 = 8 * ((l & 7) ^ (l >> 3));
  const u16* gS0;
  size_t kstep;
  if (!isV) {
    gS0 = Q + (size_t)(b * 2048 + r0) * 1024 + h * 64 + sch8;
    kstep = 1024;
  } else {
    gS0 = Qt + (size_t)(h * 64 + r0) * 4096 + b * 2048 + sch8;
    kstep = 1;
  }
  const u16* gS1 = gS0 + (size_t)8 * (isV ? 4096 : 1024);
  const int ldst = isV * 4096 + wl * 1024;

  v8s qb[4];
#pragma unroll
  for (int t = 0; t < 4; t++) {
    v8s v = *(const v8s*)(Q + (rowQ + l31) * 1024 + h * 64 + t * 16 + hi * 8);
#pragma unroll
    for (int j = 0; j < 8; j++) v[j] = (short)f2bf(bf2f((u16)v[j]) * cexp);
    qb[t] = v;
  }

  v16f o0, o1;
#pragma unroll
  for (int r = 0; r < 16; r++) { o0[r] = 0.f; o1[r] = 0.f; }
  float ls = 0.f;

  gl_lds16(gS0, &KV[0][ldst]);
  gl_lds16(gS1, &KV[0][ldst + 512]);

  int cur = 0;
  for (int kb = 0; kb < 2048; kb += 64) {
    __syncthreads();
    if (kb + 64 < 2048) {
      int nxt = cur ^ 1;
      gl_lds16(gS0 + (size_t)(kb + 64) * kstep, &KV[nxt][ldst]);
      gl_lds16(gS1 + (size_t)(kb + 64) * kstep, &KV[nxt][ldst + 512]);
    }
    const u16* Ks = &KV[cur][0];
    const u16* Vt = &KV[cur][4096];

    v16f s0, s1;
#pragma unroll
    for (int r = 0; r < 16; r++) { s0[r] = 0.f; s1[r] = 0.f; }
#pragma unroll
    for (int t = 0; t < 4; t++) {
      const int c = 8 * ((2 * t + hi) ^ (l & 7));
      v8s ka0 = *(const v8s*)(Ks + l31 * 64 + c);
      v8s ka1 = *(const v8s*)(Ks + (32 + l31) * 64 + c);
      s0 = __builtin_amdgcn_mfma_f32_32x32x16_bf16(ka0, qb[t], s0, 0, 0, 0);
      s1 = __builtin_amdgcn_mfma_f32_32x32x16_bf16(ka1, qb[t], s1, 0, 0, 0);
    }

    float p0[16], p1[16];
#pragma unroll
    for (int r = 0; r < 16; r++) {
      p0[r] = __builtin_amdgcn_exp2f(s0[r]);
      p1[r] = __builtin_amdgcn_exp2f(s1[r]);
      ls += p0[r] + p1[r];
    }

#define PVSTEP(t, P) { \
      const int off = 8 * ((t) & 1); \
      uint32_t dw00 = __builtin_amdgcn_perm(fbits(P[off + 1]), fbits(P[off + 0]), 0x07060302u); \
      uint32_t dw01 = __builtin_amdgcn_perm(fbits(P[off + 3]), fbits(P[off + 2]), 0x07060302u); \
      uint32_t dw10 = __builtin_amdgcn_perm(fbits(P[off + 5]), fbits(P[off + 4]), 0x07060302u); \
      uint32_t dw11 = __builtin_amdgcn_perm(fbits(P[off + 7]), fbits(P[off + 6]), 0x07060302u); \
      v2u sA = __builtin_amdgcn_permlane32_swap(dw00, dw10, false, false); \
      v2u sB = __builtin_amdgcn_permlane32_swap(dw01, dw11, false, false); \
      union { uint32_t u[4]; v8s v; } pa; \
      pa.u[0] = sA[0]; pa.u[1] = sB[0]; pa.u[2] = sA[1]; pa.u[3] = sB[1]; \
      const int c = 8 * ((2 * (t) + hi) ^ (l & 7)); \
      v8s vb0 = *(const v8s*)(Vt + l31 * 64 + c); \
      v8s vb1 = *(const v8s*)(Vt + (32 + l31) * 64 + c); \
      o0 = __builtin_amdgcn_mfma_f32_32x32x16_bf16(pa.v, vb0, o0, 0, 0, 0); \
      o1 = __builtin_amdgcn_mfma_f32_32x32x16_bf16(pa.v, vb1, o1, 0, 0, 0); }
    PVSTEP(0, p0)
    PVSTEP(1, p0)
    PVSTEP(2, p1)
    PVSTEP(3, p1)
#undef PVSTEP
    cur ^= 1;
  }

  ls += __shfl_xor(ls, 32, 64);   // den[q] at lanes with l31 == q

  const int hiq = hi * 4;
#pragma unroll
  for (int r = 0; r < 16; r++) {
    const int qo = (r & 3) + 8 * (r >> 2) + hiq;
    float den = __shfl(ls, qo, 64);
    float rden = 1.f / den;
    O[(rowQ + qo) * 1024 + h * 64 + l31] = f2bf(o0[r] * rden);
    O[(rowQ + qo) * 1024 + h * 64 + 32 + l31] = f2bf(o1[r] * rden);
  }
}

// ---------------------------------------------------------------------------
// out = LayerNorm(Y [+ Y2 + Y3 + Y4] + Xr) * g + b; row length 1024; dtype
// flags (1 = fp32, 0 = bf16). Y2/Y3/Y4 nullable (Y3/Y4 always bf16).
// In-place safe.
// ---------------------------------------------------------------------------
__global__ __launch_bounds__(256) void ln_residual(
    const void* __restrict__ Y, const void* __restrict__ Y2,
    const void* __restrict__ Y3, const void* __restrict__ Y4,
    const void* __restrict__ Xr,
    const float* __restrict__ g, const float* __restrict__ bb,
    void* __restrict__ out, int yf, int y2f, int xf, int of) {
  const int row = blockIdx.x, tid = threadIdx.x;
  const size_t base = (size_t)row * 1024;
  float v[4], s = 0.f, sq = 0.f;
#pragma unroll
  for (int i = 0; i < 4; i++) {
    int c = tid + i * 256;
    float ya = yf ? ((const float*)Y)[base + c] : bf2f(((const u16*)Y)[base + c]);
    float xa = xf ? ((const float*)Xr)[base + c] : bf2f(((const u16*)Xr)[base + c]);
    float x = ya + xa;
    if (Y2) {
      float y2a = y2f ? ((const float*)Y2)[base + c] : bf2f(((const u16*)Y2)[base + c]);
      x += y2a;
    }
    if (Y3) x += bf2f(((const u16*)Y3)[base + c]);
    if (Y4) x += bf2f(((const u16*)Y4)[base + c]);
    v[i] = x; s += x; sq += x * x;
  }
#pragma unroll
  for (int off = 32; off >= 1; off >>= 1) {
    s += __shfl_down(s, off, 64);
    sq += __shfl_down(sq, off, 64);
  }
  __shared__ float rs[4], rq[4];
  const int w = tid >> 6, l = tid & 63;
  if (l == 0) { rs[w] = s; rq[w] = sq; }
  __syncthreads();
  s = rs[0] + rs[1] + rs[2] + rs[3];
  sq = rq[0] + rq[1] + rq[2] + rq[3];
  const float mu = s * (1.f / 1024.f);
  const float var = sq * (1.f / 1024.f) - mu * mu;
  const float rstd = rsqrtf(var + 1e-5f);
#pragma unroll
  for (int i = 0; i < 4; i++) {
    int c = tid + i * 256;
    float r = (v[i] - mu) * rstd * g[c] + bb[c];
    if (of) ((float*)out)[base + c] = r;
    else ((u16*)out)[base + c] = f2bf(r);
  }
}

// ---------------------------------------------------------------------------
extern "C" void kernel_launch(void* const* d_in, const int* in_sizes, int n_in,
                              void* d_out, int out_size, void* d_ws, size_t ws_size,
                              hipStream_t stream) {
  const float* x   = (const float*)d_in[0];
  const float* Wq  = (const float*)d_in[1];
  const float* bq  = (const float*)d_in[2];
  const float* Wo  = (const float*)d_in[3];
  const float* bo  = (const float*)d_in[4];
  const float* g1  = (const float*)d_in[5];
  const float* be1 = (const float*)d_in[6];
  const float* W1  = (const float*)d_in[7];
  const float* b1  = (const float*)d_in[8];
  const float* W2  = (const float*)d_in[9];
  const float* b2  = (const float*)d_in[10];
  const float* g2  = (const float*)d_in[11];
  const float* be2 = (const float*)d_in[12];
  float* out = (float*)d_out;
  u16* ws  = (u16*)d_ws;

  const size_t M1 = 1048576;
  dim3 blk(256);
  dim3 blk8(512);
  const bool big = ws_size >= (size_t)37 * M1 * 2;  // 74 MiB

  if (big) {
    u16* xb   = ws + 0;          // [0..4M)  -> attn -> P2_ffn2
    u16* Qb   = ws + 4 * M1;     // [4..8M)  -> x1
    u16* Qt   = ws + 8 * M1;     // [8..12M) -> Yb (Wo P0) -> P1_ffn2
    u16* WqT  = ws + 12 * M1;    // [12..13M) -> WoT
    u16* W1T  = ws + 13 * M1;    // [13..17M) P1_wo -> W1T -> P3_ffn2
    u16* W2T  = ws + 17 * M1;    // [17..21M) P2_wo -> W2T
    u16* Hh   = ws + 21 * M1;    // [21..37M) P3_wo (head) -> Hh
    u16* attn = xb;  u16* Yb = Qt;  u16* x1 = Qb;  u16* WoT = WqT;
    // Wo split-4 partials: dead regions until later writers run (all after LN1)
    u16* P1wo = W1T;             // overwritten by transpose(W1) after LN1
    u16* P2wo = W2T;             // overwritten by transpose(W2) after FFN1
    u16* P3wo = Hh;              // overwritten by FFN1 after LN1
    // FFN2 split-4 partials: dead after their last reads
    u16* P1f2 = Qt;              // Yb dead after LN1
    u16* P2f2 = xb;              // attn dead after Wo-proj
    u16* P3f2 = W1T;             // W1T dead after FFN1

    cvt_f2b<<<dim3(4096), blk, 0, stream>>>(x, xb, 1048576);
    transpose_f2b<<<dim3(32, 32), blk, 0, stream>>>(Wq, WqT, 1024, 1024, 1024, 1024);
    gemm_g2<<<dim3(16, 32), blk, 0, stream>>>(xb, WqT, bq, Qb, 4096, 1024, 1024, 0, 0, 0);

    transpose_b2b<<<dim3(32, 128), blk, 0, stream>>>(Qb, Qt, 4096, 1024, 1024, 4096);
    attn_kernel<<<dim3(8, 32), blk8, 0, stream>>>(Qb, Qt, attn);

    // Wo projection: split-K=4 phase-pipelined 256x256, P0 -> Yb (bf16, +bias)
    transpose_f2b<<<dim3(32, 32), blk, 0, stream>>>(Wo, WoT, 1024, 1024, 1024, 1024);
    gemm_8p<<<dim3(4, 16, 4), blk8, 0, stream>>>(attn, WoT, bo, Yb, P1wo, P2wo, P3wo,
                                                 4096, 1024, 1024, 256, 0, 0);
    ln_residual<<<dim3(4096), blk, 0, stream>>>(Yb, P1wo, P2wo, P3wo, x, g1, be1, x1,
                                                0, 0, 1, 0);

    // FFN1: full-K phase-pipelined 256x256 (grid 256 = 1 block/CU)
    transpose_f2b<<<dim3(128, 32), blk, 0, stream>>>(W1, W1T, 1024, 4096, 4096, 1024);
    gemm_8p<<<dim3(16, 16, 1), blk8, 0, stream>>>(x1, W1T, b1, Hh,
                                                  nullptr, nullptr, nullptr,
                                                  4096, 4096, 1024, 1024, 1, 0);

    // FFN2: split-K=4 phase-pipelined 256x256, P0 -> out (fp32, +bias)
    transpose_f2b<<<dim3(32, 128), blk, 0, stream>>>(W2, W2T, 4096, 1024, 1024, 4096);
    gemm_8p<<<dim3(4, 16, 4), blk8, 0, stream>>>(Hh, W2T, b2, out, P1f2, P2f2, P3f2,
                                                 4096, 1024, 4096, 1024, 0, 1);

    ln_residual<<<dim3(4096), blk, 0, stream>>>(out, P1f2, P2f2, P3f2, x1, g2, be2, out,
                                                1, 0, 0, 1);
  } else {
    u16* xb   = ws + 0;
    u16* Qb   = ws + 4 * M1;
    u16* Qt   = ws + 8 * M1;
    u16* attn = xb;  u16* Yb = Qt;  u16* x1 = Qb;  u16* Hc = xb;
    u16* Wt1  = ws + 12 * M1;
    u16* Wt2  = ws + 13 * M1;

    cvt_f2b<<<dim3(4096), blk, 0, stream>>>(x, xb, 1048576);
    transpose_f2b<<<dim3(32, 32), blk, 0, stream>>>(Wq, Wt1, 1024, 1024, 1024, 1024);
    gemm_g2<<<dim3(16, 32), blk, 0, stream>>>(xb, Wt1, bq, Qb, 4096, 1024, 1024, 0, 0, 0);

    transpose_b2b<<<dim3(32, 128), blk, 0, stream>>>(Qb, Qt, 4096, 1024, 1024, 4096);
    attn_kernel<<<dim3(8, 32), blk8, 0, stream>>>(Qb, Qt, attn);

    transpose_f2b<<<dim3(32, 32), blk, 0, stream>>>(Wo, Wt2, 1024, 1024, 1024, 1024);
    gemm_g2<<<dim3(16, 32), blk, 0, stream>>>(attn, Wt2, bo, Yb, 4096, 1024, 1024, 0, 0, 0);
    ln_residual<<<dim3(4096), blk, 0, stream>>>(Yb, nullptr, nullptr, nullptr, x, g1, be1,
                                                x1, 0, 0, 1, 0);

    for (int c = 0; c < 4; c++) {
      transpose_f2b<<<dim3(32, 32), blk, 0, stream>>>(W1 + (size_t)c * 1024, Wt1,
                                                      1024, 1024, 4096, 1024);
      gemm_g2<<<dim3(16, 32), blk, 0, stream>>>(x1, Wt1, b1 + (size_t)c * 1024, Hc,
                                                4096, 1024, 1024, 1, 0, 0);
      transpose_f2b<<<dim3(32, 32), blk, 0, stream>>>(W2 + (size_t)c * M1, Wt2,
                                                      1024, 1024, 1024, 1024);
      gemm_g2<<<dim3(16, 32), blk, 0, stream>>>(Hc, Wt2, (c == 0) ? b2 : (const float*)nullptr,
                                                out, 4096, 1024, 1024, 0, (c > 0) ? 1 : 0, 1);
    }
    ln_residual<<<dim3(4096), blk, 0, stream>>>(out, nullptr, nullptr, nullptr, x1, g2, be2,
                                                out, 1, 0, 0, 1);
  }
}

// Round 7
// 329.767 us; speedup vs baseline: 1.1633x; 1.0222x over previous
//
#include <hip/hip_runtime.h>
#include <stdint.h>

// B=2, S=2048, D=1024, H=16, DK=64, DH=4096. I/O fp32; internals bf16 MFMA.
// R14: gemm_8p with wait-at-consumption counted vmcnt. R13's per-phase
// barrier lockstep regressed (50.2 vs R10's 47.7); its ledger also gave
// B23 only 1 phase of flight. Now: 2 barriers/tile, vmcnt(2)@Ph1-top,
// vmcnt(6)@Ph3-top, all loads >=3 phases in flight, MFQ(1,0) overlaps the
// tile-boundary drain. XCD swizzle kept (FETCH 74->25 MB, proven R13).
// Attention: R12 32x32 in-register-P. Split-K=4 + LN-fold from R9.

typedef unsigned short u16;
typedef __attribute__((ext_vector_type(8))) short v8s;   // 8 x bf16
typedef __attribute__((ext_vector_type(4))) float v4f;
typedef __attribute__((ext_vector_type(16))) float v16f;
typedef __attribute__((ext_vector_type(2))) unsigned int v2u;

#define AS1 __attribute__((address_space(1)))
#define AS3 __attribute__((address_space(3)))

__device__ __forceinline__ void gl_lds16(const u16* g, u16* l) {
  __builtin_amdgcn_global_load_lds((const AS1 void*)g, (AS3 void*)l, 16, 0, 0);
}

__device__ __forceinline__ float bf2f(u16 u) {
  union { uint32_t i; float f; } v; v.i = ((uint32_t)u) << 16; return v.f;
}
__device__ __forceinline__ u16 f2bf(float f) {
  union { float f; uint32_t i; } v; v.f = f;
  uint32_t x = v.i;
  return (u16)((x + 0x7FFFu + ((x >> 16) & 1u)) >> 16);  // RNE
}
__device__ __forceinline__ uint32_t fbits(float f) {
  union { float f; uint32_t u; } v; v.f = f; return v.u;
}

// ---------------------------------------------------------------------------
__global__ __launch_bounds__(256) void cvt_f2b(
    const float* __restrict__ src, u16* __restrict__ dst, int n4) {
  int i = (blockIdx.x * 256 + threadIdx.x);
  if (i < n4) {
    float4 v = *(const float4*)(src + (size_t)i * 4);
    ushort4 o;
    o.x = f2bf(v.x); o.y = f2bf(v.y); o.z = f2bf(v.z); o.w = f2bf(v.w);
    *(ushort4*)(dst + (size_t)i * 4) = o;
  }
}

// ---------------------------------------------------------------------------
__global__ __launch_bounds__(256) void transpose_f2b(
    const float* __restrict__ src, u16* __restrict__ dst,
    int R, int C, int ld_s, int ld_d) {
  __shared__ float tile[32][33];
  const int tx = threadIdx.x & 31, ty = threadIdx.x >> 5;
  const int c0 = blockIdx.x * 32, r0 = blockIdx.y * 32;
#pragma unroll
  for (int j = 0; j < 32; j += 8)
    tile[ty + j][tx] = src[(size_t)(r0 + ty + j) * ld_s + c0 + tx];
  __syncthreads();
#pragma unroll
  for (int j = 0; j < 32; j += 8)
    dst[(size_t)(c0 + ty + j) * ld_d + r0 + tx] = f2bf(tile[tx][ty + j]);
}

__global__ __launch_bounds__(256) void transpose_b2b(
    const u16* __restrict__ src, u16* __restrict__ dst,
    int R, int C, int ld_s, int ld_d) {
  __shared__ u16 tile[32][33];
  const int tx = threadIdx.x & 31, ty = threadIdx.x >> 5;
  const int c0 = blockIdx.x * 32, r0 = blockIdx.y * 32;
#pragma unroll
  for (int j = 0; j < 32; j += 8)
    tile[ty + j][tx] = src[(size_t)(r0 + ty + j) * ld_s + c0 + tx];
  __syncthreads();
#pragma unroll
  for (int j = 0; j < 32; j += 8)
    dst[(size_t)(c0 + ty + j) * ld_d + r0 + tx] = tile[tx][ty + j];
}

// ---------------------------------------------------------------------------
// gemm_8p: 256x256 tile, BK=64, 512 threads (8 waves: 2M x 4N), 128 KiB LDS.
// Wait-at-consumption schedule (2 barriers/K-tile):
//   Ph1: VMC(2)+bar -> LDA0/LDB0 ; stage A02(t+1) ; MFQ(0,0)
//   Ph2:              LDB1       ; stage B01+B23(t+1) ; MFQ(0,1)
//   Ph3: VMC(6)+bar -> LDA1      ; stage A13(t+1) ; MFQ(1,1)
//   Ph4:              MFQ(1,0)   (overlaps next tile-boundary drain)
// Ledger: in-flight peaks at 8 loads; A02/B01: 4/3 phases, B23: 3, A13: 4.
// blockIdx swizzled XCD-aware (bijective; nwg%8==0 for all launches).
// z==0 -> C0 (+bias, relu, fp32 or bf16); z=1..3 -> C1/C2/C3 bf16 partials.
// ---------------------------------------------------------------------------
__global__ __launch_bounds__(512, 1) void gemm_8p(
    const u16* __restrict__ A, const u16* __restrict__ Bt,
    const float* __restrict__ bias, void* __restrict__ C0,
    u16* __restrict__ C1, u16* __restrict__ C2, u16* __restrict__ C3,
    int M, int N, int ldk, int klen, int relu, int c0_f32) {
  __shared__ u16 As[2][16384];   // [buf][row*64 + elem], 256 rows x 64 k
  __shared__ u16 Bs[2][16384];
  const int tid = threadIdx.x;
  const int w = tid >> 6, l = tid & 63;
  const int l16 = l & 15, kgrp = (l >> 4) & 3;
  const int wm = w >> 2, wn = w & 3;

  // XCD-aware bijective swizzle over full linear id (all launches nwg%8==0)
  const int gx = gridDim.x, gyd = gridDim.y;
  const int nxy = gx * gyd;
  const int nwg = nxy * gridDim.z;
  int lin = blockIdx.x + gx * (blockIdx.y + gyd * blockIdx.z);
  if ((nwg & 7) == 0) lin = (lin & 7) * (nwg >> 3) + (lin >> 3);
  const int z = lin / nxy;
  const int rem = lin - z * nxy;
  const int by = rem / gx;
  const int bx = rem - by * gx;
  const int m0 = by * 256, n0 = bx * 256;
  const int NT = klen >> 6;

  const int rl = tid >> 3;
  const int sw = 8 * ((tid & 7) ^ (rl & 7));
  const u16* gA[4]; const u16* gB[4];
#pragma unroll
  for (int j = 0; j < 4; j++) {
    gA[j] = A + (size_t)(m0 + j * 64 + rl) * ldk + (size_t)z * klen + sw;
    gB[j] = Bt + (size_t)(n0 + j * 64 + rl) * ldk + (size_t)z * klen + sw;
  }
  const int sdst = w * 512;   // wave-uniform LDS base (+ j*4096)

  const int ch0 = 8 * ((kgrp) ^ (l16 & 7));
  const int ch1 = 8 * ((4 + kgrp) ^ (l16 & 7));
  const int abase = (wm * 128 + l16) * 64;
  const int bbase = (wn * 64 + l16) * 64;

  v4f acc[8][4];
#pragma unroll
  for (int i = 0; i < 8; i++)
#pragma unroll
    for (int j = 0; j < 4; j++)
#pragma unroll
      for (int r = 0; r < 4; r++) acc[i][j][r] = 0.f;

  v8s a[4][2], b[4][2];

#define FENCE() asm volatile("" ::: "memory")
#define VMC(n) asm volatile("s_waitcnt vmcnt(" #n ")" ::: "memory")
#define BARX() { __builtin_amdgcn_s_barrier(); \
                 __builtin_amdgcn_sched_barrier(0); FENCE(); }
#define STGA(q, j, kt) gl_lds16(gA[j] + (size_t)(kt) * 64, &As[q][(j) * 4096 + sdst])
#define STGB(q, j, kt) gl_lds16(gB[j] + (size_t)(kt) * 64, &Bs[q][(j) * 4096 + sdst])
#define LDA(p, mh) { \
  const u16* Ap = &As[p][abase + (mh) * 4096]; \
  _Pragma("unroll") for (int mi = 0; mi < 4; mi++) { \
    a[mi][0] = *(const v8s*)(Ap + mi * 1024 + ch0); \
    a[mi][1] = *(const v8s*)(Ap + mi * 1024 + ch1); } }
#define LDB(p, nh) { \
  const u16* Bp = &Bs[p][bbase + (nh) * 2048]; \
  _Pragma("unroll") for (int ni = 0; ni < 2; ni++) { \
    b[(nh) * 2 + ni][0] = *(const v8s*)(Bp + ni * 1024 + ch0); \
    b[(nh) * 2 + ni][1] = *(const v8s*)(Bp + ni * 1024 + ch1); } }
#define MFQ(mh, nh) { \
  __builtin_amdgcn_s_setprio(1); \
  _Pragma("unroll") for (int ks = 0; ks < 2; ks++) \
  _Pragma("unroll") for (int mi = 0; mi < 4; mi++) \
  _Pragma("unroll") for (int ni = 0; ni < 2; ni++) \
    acc[(mh) * 4 + mi][(nh) * 2 + ni] = __builtin_amdgcn_mfma_f32_16x16x32_bf16( \
        a[mi][ks], b[(nh) * 2 + ni][ks], acc[(mh) * 4 + mi][(nh) * 2 + ni], 0, 0, 0); \
  __builtin_amdgcn_s_setprio(0); }

  // prologue: stage tile 0 into buf0, need-first order: A02, B01, B23, A13.
  // Loop-top VMC(2) retires the first six; A13(0) rides into Ph3.
  STGA(0, 0, 0); STGA(0, 2, 0);
  FENCE();
  STGB(0, 0, 0); STGB(0, 1, 0);
  FENCE();
  STGB(0, 2, 0); STGB(0, 3, 0);
  FENCE();
  STGA(0, 1, 0); STGA(0, 3, 0);

  int p = 0;
  for (int kt = 0; kt < NT - 1; ++kt, p ^= 1) {
    const int q = p ^ 1;
    const int kn = kt + 1;
    // Ph1: A02/B01/B23(kt) landed; A13(kt) still in flight
    VMC(2); BARX();
    LDA(p, 0);
    LDB(p, 0);
    FENCE();
    STGA(q, 0, kn); STGA(q, 2, kn);
    MFQ(0, 0);
    // Ph2: issue all B stages of kt+1 (B23 gets 3 phases of flight)
    LDB(p, 1);
    FENCE();
    STGB(q, 0, kn); STGB(q, 1, kn);
    STGB(q, 2, kn); STGB(q, 3, kn);
    MFQ(0, 1);
    // Ph3: retire A13(kt) (oldest 2 of 8 in flight)
    VMC(6); BARX();
    LDA(p, 1);
    FENCE();
    STGA(q, 1, kn); STGA(q, 3, kn);
    MFQ(1, 1);
    // Ph4: pure MFMA; next tile-boundary drain overlaps this cluster
    MFQ(1, 0);
  }
  // peeled last tile: drain everything; no staging.
  VMC(0); BARX();
  LDA(p, 0);
  LDB(p, 0);
  MFQ(0, 0);
  LDB(p, 1);
  MFQ(0, 1);
  LDA(p, 1);
  MFQ(1, 1);
  MFQ(1, 0);

#undef FENCE
#undef VMC
#undef BARX
#undef STGA
#undef STGB
#undef LDA
#undef LDB
#undef MFQ

#pragma unroll
  for (int mi = 0; mi < 8; mi++) {
    const int row = m0 + wm * 128 + mi * 16 + kgrp * 4;
#pragma unroll
    for (int ni = 0; ni < 4; ni++) {
      const int col = n0 + wn * 64 + ni * 16 + l16;
      float bv = (bias && z == 0) ? bias[col] : 0.f;
#pragma unroll
      for (int r = 0; r < 4; r++) {
        float v = acc[mi][ni][r] + bv;
        if (z == 0 && relu) v = fmaxf(v, 0.f);
        size_t idx = (size_t)(row + r) * N + col;
        if (z == 0) {
          if (c0_f32) ((float*)C0)[idx] = v;
          else ((u16*)C0)[idx] = f2bf(v);
        } else if (z == 1) {
          C1[idx] = f2bf(v);
        } else if (z == 2) {
          C2[idx] = f2bf(v);
        } else {
          C3[idx] = f2bf(v);
        }
      }
    }
  }
}

// ---------------------------------------------------------------------------
// G2: 128x64 tile, BK=64, double-buffered (Qproj + small path).
// ---------------------------------------------------------------------------
__global__ __launch_bounds__(256) void gemm_g2(
    const u16* __restrict__ A, const u16* __restrict__ Bt,
    const float* __restrict__ bias, void* __restrict__ C,
    int M, int N, int K, int relu, int accum, int out_f32) {
  __shared__ u16 As[2][8192];
  __shared__ u16 Bs[2][4096];
  const int tid = threadIdx.x;
  const int w = tid >> 6, l = tid & 63;
  const int l16 = l & 15, kgrp = l >> 4;
  const int m0 = blockIdx.y * 128, n0 = blockIdx.x * 64;
  const int wr = (w >> 1) * 64, wc = (w & 1) * 32;

  const int srow = w * 8 + (l >> 3);
  const u16* gA[4];
#pragma unroll
  for (int i = 0; i < 4; i++) {
    int r = i * 32 + srow;
    gA[i] = A + (size_t)(m0 + r) * K + 8 * ((l & 7) ^ (r & 7));
  }
  const u16* gB[2];
#pragma unroll
  for (int i = 0; i < 2; i++) {
    int r = i * 32 + srow;
    gB[i] = Bt + (size_t)(n0 + r) * K + 8 * ((l & 7) ^ (r & 7));
  }

  v4f acc[4][2];
#pragma unroll
  for (int i = 0; i < 4; i++)
#pragma unroll
    for (int j = 0; j < 2; j++)
#pragma unroll
      for (int r = 0; r < 4; r++) acc[i][j][r] = 0.f;

#pragma unroll
  for (int i = 0; i < 4; i++) gl_lds16(gA[i], &As[0][(i * 256 + w * 64) * 8]);
#pragma unroll
  for (int i = 0; i < 2; i++) gl_lds16(gB[i], &Bs[0][(i * 256 + w * 64) * 8]);

  int cur = 0;
  for (int k0 = 0; k0 < K; k0 += 64) {
    __syncthreads();
    if (k0 + 64 < K) {
      int nxt = cur ^ 1;
#pragma unroll
      for (int i = 0; i < 4; i++)
        gl_lds16(gA[i] + k0 + 64, &As[nxt][(i * 256 + w * 64) * 8]);
#pragma unroll
      for (int i = 0; i < 2; i++)
        gl_lds16(gB[i] + k0 + 64, &Bs[nxt][(i * 256 + w * 64) * 8]);
    }
    v8s a[4][2], b[2][2];
#pragma unroll
    for (int ks = 0; ks < 2; ks++) {
      int ch = 8 * ((ks * 4 + kgrp) ^ (l16 & 7));
#pragma unroll
      for (int mi = 0; mi < 4; mi++)
        a[mi][ks] = *(const v8s*)(&As[cur][(wr + mi * 16 + l16) * 64 + ch]);
#pragma unroll
      for (int ni = 0; ni < 2; ni++)
        b[ni][ks] = *(const v8s*)(&Bs[cur][(wc + ni * 16 + l16) * 64 + ch]);
    }
#pragma unroll
    for (int ks = 0; ks < 2; ks++)
#pragma unroll
      for (int mi = 0; mi < 4; mi++)
#pragma unroll
        for (int ni = 0; ni < 2; ni++)
          acc[mi][ni] = __builtin_amdgcn_mfma_f32_16x16x32_bf16(a[mi][ks], b[ni][ks], acc[mi][ni], 0, 0, 0);
    cur ^= 1;
  }

#pragma unroll
  for (int ni = 0; ni < 2; ni++) {
    int col = n0 + wc + ni * 16 + l16;
    float bv = bias ? bias[col] : 0.f;
#pragma unroll
    for (int mi = 0; mi < 4; mi++) {
      int row = m0 + wr + mi * 16 + kgrp * 4;
#pragma unroll
      for (int r = 0; r < 4; r++) {
        float v = acc[mi][ni][r] + bv;
        if (relu) v = fmaxf(v, 0.f);
        size_t idx = (size_t)(row + r) * N + col;
        if (out_f32) {
          float* Cf = (float*)C;
          if (accum) v += Cf[idx];
          Cf[idx] = v;
        } else {
          ((u16*)C)[idx] = f2bf(v);
        }
      }
    }
  }
}

// ---------------------------------------------------------------------------
// Attention: O = softmax(Q Q^T / sqrt(S)) Q per (b,h).
// R12: 512 threads, 8 waves x 32 Q-rows (256-row blocks), 32x32x16 MFMA,
// P fully in-register (perm-pack + permlane32_swap). Grid (8, 32) = 256.
// ---------------------------------------------------------------------------
__global__ __launch_bounds__(512) void attn_kernel(
    const u16* __restrict__ Q, const u16* __restrict__ Qt,
    u16* __restrict__ O) {
  __shared__ u16 KV[2][8192];
  const int tid = threadIdx.x;
  const int w = tid >> 6, l = tid & 63;
  const int l31 = l & 31, hi = l >> 5;
  const int bh = blockIdx.y, b = bh >> 4, h = bh & 15;
  const int q0 = blockIdx.x * 256;
  const size_t rowQ = (size_t)(b * 2048 + q0 + w * 32);
  const float cexp = 1.4426950408889634f / 45.254833995939045f;

  const int isV = w >> 2, wl = w & 3;
  const int r0 = wl * 16 + (l >> 3);
  const int sch8 = 8 * ((l & 7) ^ (l >> 3));
  const u16* gS0;
  size_t kstep;
  if (!isV) {
    gS0 = Q + (size_t)(b * 2048 + r0) * 1024 + h * 64 + sch8;
    kstep = 1024;
  } else {
    gS0 = Qt + (size_t)(h * 64 + r0) * 4096 + b * 2048 + sch8;
    kstep = 1;
  }
  const u16* gS1 = gS0 + (size_t)8 * (isV ? 4096 : 1024);
  const int ldst = isV * 4096 + wl * 1024;

  v8s qb[4];
#pragma unroll
  for (int t = 0; t < 4; t++) {
    v8s v = *(const v8s*)(Q + (rowQ + l31) * 1024 + h * 64 + t * 16 + hi * 8);
#pragma unroll
    for (int j = 0; j < 8; j++) v[j] = (short)f2bf(bf2f((u16)v[j]) * cexp);
    qb[t] = v;
  }

  v16f o0, o1;
#pragma unroll
  for (int r = 0; r < 16; r++) { o0[r] = 0.f; o1[r] = 0.f; }
  float ls = 0.f;

  gl_lds16(gS0, &KV[0][ldst]);
  gl_lds16(gS1, &KV[0][ldst + 512]);

  int cur = 0;
  for (int kb = 0; kb < 2048; kb += 64) {
    __syncthreads();
    if (kb + 64 < 2048) {
      int nxt = cur ^ 1;
      gl_lds16(gS0 + (size_t)(kb + 64) * kstep, &KV[nxt][ldst]);
      gl_lds16(gS1 + (size_t)(kb + 64) * kstep, &KV[nxt][ldst + 512]);
    }
    const u16* Ks = &KV[cur][0];
    const u16* Vt = &KV[cur][4096];

    v16f s0, s1;
#pragma unroll
    for (int r = 0; r < 16; r++) { s0[r] = 0.f; s1[r] = 0.f; }
#pragma unroll
    for (int t = 0; t < 4; t++) {
      const int c = 8 * ((2 * t + hi) ^ (l & 7));
      v8s ka0 = *(const v8s*)(Ks + l31 * 64 + c);
      v8s ka1 = *(const v8s*)(Ks + (32 + l31) * 64 + c);
      s0 = __builtin_amdgcn_mfma_f32_32x32x16_bf16(ka0, qb[t], s0, 0, 0, 0);
      s1 = __builtin_amdgcn_mfma_f32_32x32x16_bf16(ka1, qb[t], s1, 0, 0, 0);
    }

    float p0[16], p1[16];
#pragma unroll
    for (int r = 0; r < 16; r++) {
      p0[r] = __builtin_amdgcn_exp2f(s0[r]);
      p1[r] = __builtin_amdgcn_exp2f(s1[r]);
      ls += p0[r] + p1[r];
    }

#define PVSTEP(t, P) { \
      const int off = 8 * ((t) & 1); \
      uint32_t dw00 = __builtin_amdgcn_perm(fbits(P[off + 1]), fbits(P[off + 0]), 0x07060302u); \
      uint32_t dw01 = __builtin_amdgcn_perm(fbits(P[off + 3]), fbits(P[off + 2]), 0x07060302u); \
      uint32_t dw10 = __builtin_amdgcn_perm(fbits(P[off + 5]), fbits(P[off + 4]), 0x07060302u); \
      uint32_t dw11 = __builtin_amdgcn_perm(fbits(P[off + 7]), fbits(P[off + 6]), 0x07060302u); \
      v2u sA = __builtin_amdgcn_permlane32_swap(dw00, dw10, false, false); \
      v2u sB = __builtin_amdgcn_permlane32_swap(dw01, dw11, false, false); \
      union { uint32_t u[4]; v8s v; } pa; \
      pa.u[0] = sA[0]; pa.u[1] = sB[0]; pa.u[2] = sA[1]; pa.u[3] = sB[1]; \
      const int c = 8 * ((2 * (t) + hi) ^ (l & 7)); \
      v8s vb0 = *(const v8s*)(Vt + l31 * 64 + c); \
      v8s vb1 = *(const v8s*)(Vt + (32 + l31) * 64 + c); \
      o0 = __builtin_amdgcn_mfma_f32_32x32x16_bf16(pa.v, vb0, o0, 0, 0, 0); \
      o1 = __builtin_amdgcn_mfma_f32_32x32x16_bf16(pa.v, vb1, o1, 0, 0, 0); }
    PVSTEP(0, p0)
    PVSTEP(1, p0)
    PVSTEP(2, p1)
    PVSTEP(3, p1)
#undef PVSTEP
    cur ^= 1;
  }

  ls += __shfl_xor(ls, 32, 64);   // den[q] at lanes with l31 == q

  const int hiq = hi * 4;
#pragma unroll
  for (int r = 0; r < 16; r++) {
    const int qo = (r & 3) + 8 * (r >> 2) + hiq;
    float den = __shfl(ls, qo, 64);
    float rden = 1.f / den;
    O[(rowQ + qo) * 1024 + h * 64 + l31] = f2bf(o0[r] * rden);
    O[(rowQ + qo) * 1024 + h * 64 + 32 + l31] = f2bf(o1[r] * rden);
  }
}

// ---------------------------------------------------------------------------
// out = LayerNorm(Y [+ Y2 + Y3 + Y4] + Xr) * g + b; row length 1024; dtype
// flags (1 = fp32, 0 = bf16). Y2/Y3/Y4 nullable (Y3/Y4 always bf16).
// In-place safe.
// ---------------------------------------------------------------------------
__global__ __launch_bounds__(256) void ln_residual(
    const void* __restrict__ Y, const void* __restrict__ Y2,
    const void* __restrict__ Y3, const void* __restrict__ Y4,
    const void* __restrict__ Xr,
    const float* __restrict__ g, const float* __restrict__ bb,
    void* __restrict__ out, int yf, int y2f, int xf, int of) {
  const int row = blockIdx.x, tid = threadIdx.x;
  const size_t base = (size_t)row * 1024;
  float v[4], s = 0.f, sq = 0.f;
#pragma unroll
  for (int i = 0; i < 4; i++) {
    int c = tid + i * 256;
    float ya = yf ? ((const float*)Y)[base + c] : bf2f(((const u16*)Y)[base + c]);
    float xa = xf ? ((const float*)Xr)[base + c] : bf2f(((const u16*)Xr)[base + c]);
    float x = ya + xa;
    if (Y2) {
      float y2a = y2f ? ((const float*)Y2)[base + c] : bf2f(((const u16*)Y2)[base + c]);
      x += y2a;
    }
    if (Y3) x += bf2f(((const u16*)Y3)[base + c]);
    if (Y4) x += bf2f(((const u16*)Y4)[base + c]);
    v[i] = x; s += x; sq += x * x;
  }
#pragma unroll
  for (int off = 32; off >= 1; off >>= 1) {
    s += __shfl_down(s, off, 64);
    sq += __shfl_down(sq, off, 64);
  }
  __shared__ float rs[4], rq[4];
  const int w = tid >> 6, l = tid & 63;
  if (l == 0) { rs[w] = s; rq[w] = sq; }
  __syncthreads();
  s = rs[0] + rs[1] + rs[2] + rs[3];
  sq = rq[0] + rq[1] + rq[2] + rq[3];
  const float mu = s * (1.f / 1024.f);
  const float var = sq * (1.f / 1024.f) - mu * mu;
  const float rstd = rsqrtf(var + 1e-5f);
#pragma unroll
  for (int i = 0; i < 4; i++) {
    int c = tid + i * 256;
    float r = (v[i] - mu) * rstd * g[c] + bb[c];
    if (of) ((float*)out)[base + c] = r;
    else ((u16*)out)[base + c] = f2bf(r);
  }
}

// ---------------------------------------------------------------------------
extern "C" void kernel_launch(void* const* d_in, const int* in_sizes, int n_in,
                              void* d_out, int out_size, void* d_ws, size_t ws_size,
                              hipStream_t stream) {
  const float* x   = (const float*)d_in[0];
  const float* Wq  = (const float*)d_in[1];
  const float* bq  = (const float*)d_in[2];
  const float* Wo  = (const float*)d_in[3];
  const float* bo  = (const float*)d_in[4];
  const float* g1  = (const float*)d_in[5];
  const float* be1 = (const float*)d_in[6];
  const float* W1  = (const float*)d_in[7];
  const float* b1  = (const float*)d_in[8];
  const float* W2  = (const float*)d_in[9];
  const float* b2  = (const float*)d_in[10];
  const float* g2  = (const float*)d_in[11];
  const float* be2 = (const float*)d_in[12];
  float* out = (float*)d_out;
  u16* ws  = (u16*)d_ws;

  const size_t M1 = 1048576;
  dim3 blk(256);
  dim3 blk8(512);
  const bool big = ws_size >= (size_t)37 * M1 * 2;  // 74 MiB

  if (big) {
    u16* xb   = ws + 0;          // [0..4M)  -> attn -> P2_ffn2
    u16* Qb   = ws + 4 * M1;     // [4..8M)  -> x1
    u16* Qt   = ws + 8 * M1;     // [8..12M) -> Yb (Wo P0) -> P1_ffn2
    u16* WqT  = ws + 12 * M1;    // [12..13M) -> WoT
    u16* W1T  = ws + 13 * M1;    // [13..17M) P1_wo -> W1T -> P3_ffn2
    u16* W2T  = ws + 17 * M1;    // [17..21M) P2_wo -> W2T
    u16* Hh   = ws + 21 * M1;    // [21..37M) P3_wo (head) -> Hh
    u16* attn = xb;  u16* Yb = Qt;  u16* x1 = Qb;  u16* WoT = WqT;
    // Wo split-4 partials: dead regions until later writers run (all after LN1)
    u16* P1wo = W1T;             // overwritten by transpose(W1) after LN1
    u16* P2wo = W2T;             // overwritten by transpose(W2) after FFN1
    u16* P3wo = Hh;              // overwritten by FFN1 after LN1
    // FFN2 split-4 partials: dead after their last reads
    u16* P1f2 = Qt;              // Yb dead after LN1
    u16* P2f2 = xb;              // attn dead after Wo-proj
    u16* P3f2 = W1T;             // W1T dead after FFN1

    cvt_f2b<<<dim3(4096), blk, 0, stream>>>(x, xb, 1048576);
    transpose_f2b<<<dim3(32, 32), blk, 0, stream>>>(Wq, WqT, 1024, 1024, 1024, 1024);
    gemm_g2<<<dim3(16, 32), blk, 0, stream>>>(xb, WqT, bq, Qb, 4096, 1024, 1024, 0, 0, 0);

    transpose_b2b<<<dim3(32, 128), blk, 0, stream>>>(Qb, Qt, 4096, 1024, 1024, 4096);
    attn_kernel<<<dim3(8, 32), blk8, 0, stream>>>(Qb, Qt, attn);

    // Wo projection: split-K=4 phase-pipelined 256x256, P0 -> Yb (bf16, +bias)
    transpose_f2b<<<dim3(32, 32), blk, 0, stream>>>(Wo, WoT, 1024, 1024, 1024, 1024);
    gemm_8p<<<dim3(4, 16, 4), blk8, 0, stream>>>(attn, WoT, bo, Yb, P1wo, P2wo, P3wo,
                                                 4096, 1024, 1024, 256, 0, 0);
    ln_residual<<<dim3(4096), blk, 0, stream>>>(Yb, P1wo, P2wo, P3wo, x, g1, be1, x1,
                                                0, 0, 1, 0);

    // FFN1: full-K phase-pipelined 256x256 (grid 256 = 1 block/CU)
    transpose_f2b<<<dim3(128, 32), blk, 0, stream>>>(W1, W1T, 1024, 4096, 4096, 1024);
    gemm_8p<<<dim3(16, 16, 1), blk8, 0, stream>>>(x1, W1T, b1, Hh,
                                                  nullptr, nullptr, nullptr,
                                                  4096, 4096, 1024, 1024, 1, 0);

    // FFN2: split-K=4 phase-pipelined 256x256, P0 -> out (fp32, +bias)
    transpose_f2b<<<dim3(32, 128), blk, 0, stream>>>(W2, W2T, 4096, 1024, 1024, 4096);
    gemm_8p<<<dim3(4, 16, 4), blk8, 0, stream>>>(Hh, W2T, b2, out, P1f2, P2f2, P3f2,
                                                 4096, 1024, 4096, 1024, 0, 1);

    ln_residual<<<dim3(4096), blk, 0, stream>>>(out, P1f2, P2f2, P3f2, x1, g2, be2, out,
                                                1, 0, 0, 1);
  } else {
    u16* xb   = ws + 0;
    u16* Qb   = ws + 4 * M1;
    u16* Qt   = ws + 8 * M1;
    u16* attn = xb;  u16* Yb = Qt;  u16* x1 = Qb;  u16* Hc = xb;
    u16* Wt1  = ws + 12 * M1;
    u16* Wt2  = ws + 13 * M1;

    cvt_f2b<<<dim3(4096), blk, 0, stream>>>(x, xb, 1048576);
    transpose_f2b<<<dim3(32, 32), blk, 0, stream>>>(Wq, Wt1, 1024, 1024, 1024, 1024);
    gemm_g2<<<dim3(16, 32), blk, 0, stream>>>(xb, Wt1, bq, Qb, 4096, 1024, 1024, 0, 0, 0);

    transpose_b2b<<<dim3(32, 128), blk, 0, stream>>>(Qb, Qt, 4096, 1024, 1024, 4096);
    attn_kernel<<<dim3(8, 32), blk8, 0, stream>>>(Qb, Qt, attn);

    transpose_f2b<<<dim3(32, 32), blk, 0, stream>>>(Wo, Wt2, 1024, 1024, 1024, 1024);
    gemm_g2<<<dim3(16, 32), blk, 0, stream>>>(attn, Wt2, bo, Yb, 4096, 1024, 1024, 0, 0, 0);
    ln_residual<<<dim3(4096), blk, 0, stream>>>(Yb, nullptr, nullptr, nullptr, x, g1, be1,
                                                x1, 0, 0, 1, 0);

    for (int c = 0; c < 4; c++) {
      transpose_f2b<<<dim3(32, 32), blk, 0, stream>>>(W1 + (size_t)c * 1024, Wt1,
                                                      1024, 1024, 4096, 1024);
      gemm_g2<<<dim3(16, 32), blk, 0, stream>>>(x1, Wt1, b1 + (size_t)c * 1024, Hc,
                                                4096, 1024, 1024, 1, 0, 0);
      transpose_f2b<<<dim3(32, 32), blk, 0, stream>>>(W2 + (size_t)c * M1, Wt2,
                                                      1024, 1024, 1024, 1024);
      gemm_g2<<<dim3(16, 32), blk, 0, stream>>>(Hc, Wt2, (c == 0) ? b2 : (const float*)nullptr,
                                                out, 4096, 1024, 1024, 0, (c > 0) ? 1 : 0, 1);
    }
    ln_residual<<<dim3(4096), blk, 0, stream>>>(out, nullptr, nullptr, nullptr, x1, g2, be2,
                                                out, 1, 0, 0, 1);
  }
}